// Round 1
// baseline (3210.221 us; speedup 1.0000x reference)
//
#include <hip/hip_runtime.h>

#define B_   32
#define C_   256
#define HH   64
#define P_   4096   // 64*64
#define L_   40
#define D_   768
#define NC_  8
#define EMB_ 392
#define CP_  (C_*P_)   // 1048576

static __device__ __forceinline__ float siluf(float y) {
    return y / (1.f + expf(-y));
}

// ---------------- weight transpose prep ----------------
// WtV/WtF1/WtF3: [ic][oc] (256x256); WtF2: [tap][ic][oc] (9x256x256)
__global__ __launch_bounds__(256) void k_prep(
    const float* __restrict__ wv, const float* __restrict__ wf1,
    const float* __restrict__ wf3, const float* __restrict__ wf2,
    float* __restrict__ WtV, float* __restrict__ WtF1,
    float* __restrict__ WtF3, float* __restrict__ WtF2)
{
    int i = blockIdx.x * 256 + threadIdx.x;   // 0..65535, i = ic*256 + oc
    int ic = i >> 8, oc = i & 255;
    WtV[i]  = wv[oc * 256 + ic];
    WtF1[i] = wf1[oc * 256 + ic];
    WtF3[i] = wf3[oc * 256 + ic];
#pragma unroll
    for (int tap = 0; tap < 9; ++tap)
        WtF2[tap * 65536 + i] = wf2[oc * 2304 + ic * 9 + tap];
}

// ---------------- language path ----------------
__global__ __launch_bounds__(256) void k_lang(
    const float* __restrict__ flang, const int* __restrict__ wmask,
    const float* __restrict__ W1, const float* __restrict__ b1,
    const float* __restrict__ W2, const float* __restrict__ b2,
    int* __restrict__ centers)   // [B][NC][2] (yc, xc)
{
    int b = blockIdx.x, tid = threadIdx.x;
    __shared__ float inner[L_];
    __shared__ float cnt_s;
    __shared__ float favg[D_];
    __shared__ float hbuf[EMB_];
    __shared__ float mfs[16];

    if (tid == 0) {
        int total = 0;
        for (int l = 0; l < L_; ++l) total += wmask[b * L_ + l];
        int c = 0, cntv = 0;
        for (int l = 0; l < L_; ++l) {
            int m = wmask[b * L_ + l];
            c += m;
            float f = (m == 1 && c > 1 && c < total) ? 1.f : 0.f;
            inner[l] = f;
            cntv += (f != 0.f);
        }
        cnt_s = (float)cntv;
    }
    __syncthreads();
    float cinv = 1.f / cnt_s;
    for (int d = tid; d < D_; d += 256) {
        float s = 0.f;
        for (int l = 0; l < L_; ++l)
            s += flang[((size_t)b * L_ + l) * D_ + d] * inner[l];
        favg[d] = s * cinv;
    }
    __syncthreads();
    for (int e = tid; e < EMB_; e += 256) {
        float s = b1[e];
        const float* w = W1 + (size_t)e * D_;
        for (int d = 0; d < D_; ++d) s += w[d] * favg[d];
        hbuf[e] = s;
    }
    __syncthreads();
    if (tid < 16) {
        float s = b2[tid];
        const float* w = W2 + tid * EMB_;
        for (int d = 0; d < EMB_; ++d) s += w[d] * hbuf[d];
        mfs[tid] = 1.f / (1.f + expf(-s));
    }
    __syncthreads();
    if (tid < NC_) {
        centers[b * (NC_ * 2) + tid * 2 + 0] = (int)(mfs[tid * 2 + 0] * (float)HH);
        centers[b * (NC_ * 2) + tid * 2 + 1] = (int)(mfs[tid * 2 + 1] * (float)HH);
    }
}

// ---------------- gaussian weights -> gamma/beta -> g (mean), b (max) ----------------
__global__ __launch_bounds__(256) void k_gb(
    const int* __restrict__ centers,
    const float* __restrict__ wg, const float* __restrict__ sg, const float* __restrict__ bg,
    const float* __restrict__ wb, const float* __restrict__ sb, const float* __restrict__ bb,
    float* __restrict__ gmap, float* __restrict__ bmap)
{
    int idx = blockIdx.x * 256 + threadIdx.x;   // 0..131071
    int b = idx >> 12;
    int p = idx & 4095;
    int gy = p >> 6, gx = p & 63;

    float w[NC_];
#pragma unroll
    for (int nc = 0; nc < NC_; ++nc) {
        int yc = centers[b * (NC_ * 2) + nc * 2 + 0];
        int xc = centers[b * (NC_ * 2) + nc * 2 + 1];
        int dy = gy - yc, dx = gx - xc;
        float d2 = (float)(dy * dy + dx * dx);
        w[nc] = expf(-d2 / 81.92f);   // 2*sigma^2, sigma = 0.1*64
    }
    float gsum = 0.f, bmx = -1e30f;
#pragma unroll
    for (int c = 0; c < NC_; ++c) {
        float ag = 0.f, ab = 0.f;
#pragma unroll
        for (int ic = 0; ic < NC_; ++ic) {
            ag += wg[c * NC_ + ic] * w[ic];
            ab += wb[c * NC_ + ic] * w[ic];
        }
        float yg = sg[c] * ag + bg[c];
        gsum += tanhf(siluf(yg));
        float yb = sb[c] * ab + bb[c];
        bmx = fmaxf(bmx, tanhf(siluf(yb)));
    }
    gmap[idx] = gsum * (1.f / (float)NC_);
    bmap[idx] = bmx;
}

// ---------------- fused: map_visu conv + FiLM + l2norm -> v_film ----------------
// block: 256 threads = all 256 oc; tile: 16 pixels
__global__ __launch_bounds__(256) void k_visu_film(
    const float* __restrict__ img, const float* __restrict__ WtV,
    const float* __restrict__ s_visu, const float* __restrict__ b_visu,
    const float* __restrict__ gmap, const float* __restrict__ bmap,
    float* __restrict__ vfilm)
{
    int b = blockIdx.y;
    int p0 = blockIdx.x * 16;
    int tid = threadIdx.x;
    __shared__ float Xs[C_][16];
    __shared__ float red[4][16];
    __shared__ float inv_s[16];

    const float* imgb = img + (size_t)b * CP_;
    for (int idx = tid; idx < C_ * 16; idx += 256) {
        int ic = idx >> 4, px = idx & 15;
        Xs[ic][px] = imgb[ic * P_ + p0 + px];
    }
    __syncthreads();

    float acc[16];
#pragma unroll
    for (int p = 0; p < 16; ++p) acc[p] = 0.f;
    const int oc = tid;
#pragma unroll 4
    for (int ic = 0; ic < C_; ++ic) {
        float wv = WtV[ic * C_ + oc];
        const float4* xr = (const float4*)(&Xs[ic][0]);
        float4 x0 = xr[0], x1 = xr[1], x2 = xr[2], x3 = xr[3];
        acc[0]  += wv * x0.x; acc[1]  += wv * x0.y; acc[2]  += wv * x0.z; acc[3]  += wv * x0.w;
        acc[4]  += wv * x1.x; acc[5]  += wv * x1.y; acc[6]  += wv * x1.z; acc[7]  += wv * x1.w;
        acc[8]  += wv * x2.x; acc[9]  += wv * x2.y; acc[10] += wv * x2.z; acc[11] += wv * x2.w;
        acc[12] += wv * x3.x; acc[13] += wv * x3.y; acc[14] += wv * x3.z; acc[15] += wv * x3.w;
    }

    float sv = s_visu[oc], bv = b_visu[oc];
    float t[16];
#pragma unroll
    for (int p = 0; p < 16; ++p) {
        float y = sv * acc[p] + bv;
        float mv = tanhf(siluf(y));
        float gg = gmap[(size_t)b * P_ + p0 + p];
        float bbv = bmap[(size_t)b * P_ + p0 + p];
        t[p] = gg * mv + bbv;
    }

    int lane = tid & 63, wv_ = tid >> 6;
#pragma unroll
    for (int p = 0; p < 16; ++p) {
        float v = t[p] * t[p];
        v += __shfl_xor(v, 32);
        v += __shfl_xor(v, 16);
        v += __shfl_xor(v, 8);
        v += __shfl_xor(v, 4);
        v += __shfl_xor(v, 2);
        v += __shfl_xor(v, 1);
        if (lane == 0) red[wv_][p] = v;
    }
    __syncthreads();
    if (tid < 16) {
        float s = red[0][tid] + red[1][tid] + red[2][tid] + red[3][tid];
        inv_s[tid] = 1.f / fmaxf(sqrtf(s), 1e-12f);
    }
    __syncthreads();

    float* op = vfilm + (size_t)b * CP_ + (size_t)oc * P_ + p0;
#pragma unroll
    for (int p = 0; p < 16; p += 4) {
        float4 o = make_float4(t[p] * inv_s[p], t[p + 1] * inv_s[p + 1],
                               t[p + 2] * inv_s[p + 2], t[p + 3] * inv_s[p + 3]);
        *(float4*)(op + p) = o;
    }
}

// ---------------- tiled 1x1 conv (64 oc x 64 px) + scale/shift + silu ----------------
__global__ __launch_bounds__(256) void k_conv1x1_64(
    const float* __restrict__ X, const float* __restrict__ Wt,
    const float* __restrict__ scale, const float* __restrict__ shift,
    float* __restrict__ Y)
{
    int b = blockIdx.z;
    int oc0 = blockIdx.x * 64;
    int p0 = blockIdx.y * 64;
    int tid = threadIdx.x;
    int tx = tid & 15, ty = tid >> 4;
    __shared__ float Ws[16][64];
    __shared__ float Xs[16][64];
    const float* Xb = X + (size_t)b * CP_;

    float acc[4][4];
#pragma unroll
    for (int i = 0; i < 4; ++i)
#pragma unroll
        for (int j = 0; j < 4; ++j) acc[i][j] = 0.f;

    int lk = tid >> 4;          // 0..15
    int lc = (tid * 4) & 63;    // 0..60 step 4

    for (int k0 = 0; k0 < C_; k0 += 16) {
        *(float4*)&Ws[lk][lc] = *(const float4*)&Wt[(k0 + lk) * C_ + oc0 + lc];
        *(float4*)&Xs[lk][lc] = *(const float4*)&Xb[(k0 + lk) * P_ + p0 + lc];
        __syncthreads();
#pragma unroll
        for (int kk = 0; kk < 16; ++kk) {
            float4 a4 = *(const float4*)&Ws[kk][ty * 4];
            float4 b4 = *(const float4*)&Xs[kk][tx * 4];
            float a_[4] = {a4.x, a4.y, a4.z, a4.w};
            float b_[4] = {b4.x, b4.y, b4.z, b4.w};
#pragma unroll
            for (int i = 0; i < 4; ++i)
#pragma unroll
                for (int j = 0; j < 4; ++j)
                    acc[i][j] += a_[i] * b_[j];
        }
        __syncthreads();
    }
#pragma unroll
    for (int i = 0; i < 4; ++i) {
        int oc = oc0 + ty * 4 + i;
        float sc = scale[oc], sh = shift[oc];
        float4 o;
        o.x = siluf(sc * acc[i][0] + sh);
        o.y = siluf(sc * acc[i][1] + sh);
        o.z = siluf(sc * acc[i][2] + sh);
        o.w = siluf(sc * acc[i][3] + sh);
        *(float4*)&Y[(size_t)b * CP_ + (size_t)oc * P_ + p0 + tx * 4] = o;
    }
}

// ---------------- tiled 3x3 conv (64 oc x 64 px = one image row) ----------------
// Wt layout: [tap][ic][oc], k = tap*256 + ic
__global__ __launch_bounds__(256) void k_conv3x3_64(
    const float* __restrict__ X, const float* __restrict__ Wt,
    const float* __restrict__ scale, const float* __restrict__ shift,
    float* __restrict__ Y)
{
    int b = blockIdx.z;
    int oc0 = blockIdx.x * 64;
    int h = blockIdx.y;          // pixel tile = image row h; p0 = h*64
    int tid = threadIdx.x;
    int tx = tid & 15, ty = tid >> 4;
    __shared__ float Ws[16][64];
    __shared__ float Xs[16][64];
    const float* Xb = X + (size_t)b * CP_;

    float acc[4][4];
#pragma unroll
    for (int i = 0; i < 4; ++i)
#pragma unroll
        for (int j = 0; j < 4; ++j) acc[i][j] = 0.f;

    int lk = tid >> 4;
    int lc = (tid * 4) & 63;

    for (int k0 = 0; k0 < 9 * C_; k0 += 16) {
        int tap = k0 >> 8;
        int ic0 = k0 & 255;
        int dy = tap / 3 - 1;
        int dx = tap - (tap / 3) * 3 - 1;
        int hs = h + dy;
        bool rowok = ((unsigned)hs < (unsigned)HH);

        *(float4*)&Ws[lk][lc] = *(const float4*)&Wt[(k0 + lk) * C_ + oc0 + lc];
#pragma unroll
        for (int r = 0; r < 4; ++r) {
            int e = tid + r * 256;
            int kk = e >> 6, w = e & 63;
            int wsrc = w + dx;
            float v = 0.f;
            if (rowok && (unsigned)wsrc < (unsigned)HH)
                v = Xb[(ic0 + kk) * P_ + hs * HH + wsrc];
            Xs[kk][w] = v;
        }
        __syncthreads();
#pragma unroll
        for (int kk = 0; kk < 16; ++kk) {
            float4 a4 = *(const float4*)&Ws[kk][ty * 4];
            float4 b4 = *(const float4*)&Xs[kk][tx * 4];
            float a_[4] = {a4.x, a4.y, a4.z, a4.w};
            float b_[4] = {b4.x, b4.y, b4.z, b4.w};
#pragma unroll
            for (int i = 0; i < 4; ++i)
#pragma unroll
                for (int j = 0; j < 4; ++j)
                    acc[i][j] += a_[i] * b_[j];
        }
        __syncthreads();
    }
#pragma unroll
    for (int i = 0; i < 4; ++i) {
        int oc = oc0 + ty * 4 + i;
        float sc = scale[oc], sh = shift[oc];
        float4 o;
        o.x = siluf(sc * acc[i][0] + sh);
        o.y = siluf(sc * acc[i][1] + sh);
        o.z = siluf(sc * acc[i][2] + sh);
        o.w = siluf(sc * acc[i][3] + sh);
        *(float4*)&Y[(size_t)b * CP_ + (size_t)oc * P_ + h * HH + tx * 4] = o;
    }
}

// ---------------- fused: f3 conv + bias + v_add + l2norm -> out ----------------
__global__ __launch_bounds__(256) void k_final(
    const float* __restrict__ V2, const float* __restrict__ WtF3,
    const float* __restrict__ bias_f3, const float* __restrict__ img,
    const float* __restrict__ add_w, float* __restrict__ out)
{
    int b = blockIdx.y;
    int p0 = blockIdx.x * 16;
    int tid = threadIdx.x;
    __shared__ float Xs[C_][16];
    __shared__ float red[4][16];
    __shared__ float inv_s[16];

    const float* Vb = V2 + (size_t)b * CP_;
    for (int idx = tid; idx < C_ * 16; idx += 256) {
        int ic = idx >> 4, px = idx & 15;
        Xs[ic][px] = Vb[ic * P_ + p0 + px];
    }
    __syncthreads();

    float acc[16];
#pragma unroll
    for (int p = 0; p < 16; ++p) acc[p] = 0.f;
    const int oc = tid;
#pragma unroll 4
    for (int ic = 0; ic < C_; ++ic) {
        float wv = WtF3[ic * C_ + oc];
        const float4* xr = (const float4*)(&Xs[ic][0]);
        float4 x0 = xr[0], x1 = xr[1], x2 = xr[2], x3 = xr[3];
        acc[0]  += wv * x0.x; acc[1]  += wv * x0.y; acc[2]  += wv * x0.z; acc[3]  += wv * x0.w;
        acc[4]  += wv * x1.x; acc[5]  += wv * x1.y; acc[6]  += wv * x1.z; acc[7]  += wv * x1.w;
        acc[8]  += wv * x2.x; acc[9]  += wv * x2.y; acc[10] += wv * x2.z; acc[11] += wv * x2.w;
        acc[12] += wv * x3.x; acc[13] += wv * x3.y; acc[14] += wv * x3.z; acc[15] += wv * x3.w;
    }

    float aw = tanhf(add_w[0]);
    float c1 = 1.f + aw, c2 = 1.f - aw;
    float bf = bias_f3[oc];
    const float* imgp = img + (size_t)b * CP_ + (size_t)oc * P_ + p0;
    float4 i0 = *(const float4*)(imgp + 0);
    float4 i1 = *(const float4*)(imgp + 4);
    float4 i2 = *(const float4*)(imgp + 8);
    float4 i3 = *(const float4*)(imgp + 12);
    float iv[16] = {i0.x, i0.y, i0.z, i0.w, i1.x, i1.y, i1.z, i1.w,
                    i2.x, i2.y, i2.z, i2.w, i3.x, i3.y, i3.z, i3.w};
    float t[16];
#pragma unroll
    for (int p = 0; p < 16; ++p)
        t[p] = c1 * iv[p] + c2 * (acc[p] + bf);

    int lane = tid & 63, wv_ = tid >> 6;
#pragma unroll
    for (int p = 0; p < 16; ++p) {
        float v = t[p] * t[p];
        v += __shfl_xor(v, 32);
        v += __shfl_xor(v, 16);
        v += __shfl_xor(v, 8);
        v += __shfl_xor(v, 4);
        v += __shfl_xor(v, 2);
        v += __shfl_xor(v, 1);
        if (lane == 0) red[wv_][p] = v;
    }
    __syncthreads();
    if (tid < 16) {
        float s = red[0][tid] + red[1][tid] + red[2][tid] + red[3][tid];
        inv_s[tid] = 1.f / fmaxf(sqrtf(s), 1e-12f);
    }
    __syncthreads();

    float* op = out + (size_t)b * CP_ + (size_t)oc * P_ + p0;
#pragma unroll
    for (int p = 0; p < 16; p += 4) {
        float4 o = make_float4(t[p] * inv_s[p], t[p + 1] * inv_s[p + 1],
                               t[p + 2] * inv_s[p + 2], t[p + 3] * inv_s[p + 3]);
        *(float4*)(op + p) = o;
    }
}

extern "C" void kernel_launch(void* const* d_in, const int* in_sizes, int n_in,
                              void* d_out, int out_size, void* d_ws, size_t ws_size,
                              hipStream_t stream)
{
    const float* img     = (const float*)d_in[0];
    const float* flang   = (const float*)d_in[1];
    const int*   wmask   = (const int*)d_in[2];
    const float* w_visu  = (const float*)d_in[3];
    const float* s_visu  = (const float*)d_in[4];
    const float* b_visu  = (const float*)d_in[5];
    const float* w_g     = (const float*)d_in[6];
    const float* s_g     = (const float*)d_in[7];
    const float* b_g     = (const float*)d_in[8];
    const float* w_b     = (const float*)d_in[9];
    const float* s_b     = (const float*)d_in[10];
    const float* b_b     = (const float*)d_in[11];
    const float* W1      = (const float*)d_in[12];
    const float* b1      = (const float*)d_in[13];
    const float* W2      = (const float*)d_in[14];
    const float* b2      = (const float*)d_in[15];
    const float* w_f1    = (const float*)d_in[16];
    const float* s_f1    = (const float*)d_in[17];
    const float* b_f1    = (const float*)d_in[18];
    const float* w_f2    = (const float*)d_in[19];
    const float* s_f2    = (const float*)d_in[20];
    const float* b_f2    = (const float*)d_in[21];
    const float* w_f3    = (const float*)d_in[22];
    const float* bias_f3 = (const float*)d_in[23];
    const float* add_w   = (const float*)d_in[24];

    float* out = (float*)d_out;
    float* ws  = (float*)d_ws;

    // workspace layout (floats)
    float* big    = ws;                        // 33554432 (v_film, then v2)
    float* WtV    = big + (size_t)B_ * CP_;    // 65536
    float* WtF1   = WtV + 65536;               // 65536
    float* WtF3   = WtF1 + 65536;              // 65536
    float* WtF2   = WtF3 + 65536;              // 589824
    float* gmap   = WtF2 + 589824;             // 131072
    float* bmap   = gmap + (size_t)B_ * P_;    // 131072
    int*   centers = (int*)(bmap + (size_t)B_ * P_);  // 512 ints

    k_prep<<<256, 256, 0, stream>>>(w_visu, w_f1, w_f3, w_f2, WtV, WtF1, WtF3, WtF2);
    k_lang<<<B_, 256, 0, stream>>>(flang, wmask, W1, b1, W2, b2, centers);
    k_gb<<<(B_ * P_) / 256, 256, 0, stream>>>(centers, w_g, s_g, b_g, w_b, s_b, b_b, gmap, bmap);
    k_visu_film<<<dim3(P_ / 16, B_), 256, 0, stream>>>(img, WtV, s_visu, b_visu, gmap, bmap, big);
    k_conv1x1_64<<<dim3(C_ / 64, P_ / 64, B_), 256, 0, stream>>>(big, WtF1, s_f1, b_f1, out);
    k_conv3x3_64<<<dim3(C_ / 64, HH, B_), 256, 0, stream>>>(out, WtF2, s_f2, b_f2, big);
    k_final<<<dim3(P_ / 16, B_), 256, 0, stream>>>(big, WtF3, bias_f3, img, add_w, out);
}

// Round 2
// 2326.475 us; speedup vs baseline: 1.3799x; 1.3799x over previous
//
#include <hip/hip_runtime.h>
#include <hip/hip_bf16.h>

#define B_   32
#define C_   256
#define HH   64
#define P_   4096   // 64*64
#define L_   40
#define D_   768
#define NC_  8
#define EMB_ 392
#define CP_  (C_*P_)   // 1048576

typedef __attribute__((ext_vector_type(8))) short bf16x8;
typedef __attribute__((ext_vector_type(4))) float f32x4;
typedef unsigned short u16;

static __device__ __forceinline__ float siluf(float y) {
    return y / (1.f + expf(-y));
}
static __device__ __forceinline__ u16 f2b(float f) {
    __hip_bfloat16 h = __float2bfloat16(f);
    return *reinterpret_cast<u16*>(&h);
}

// ---------------- weight pack to bf16 ----------------
// WV/WF1/WF3: [oc][ic] ; WF2: [oc][tap*256+ic]  (K-contiguous rows)
__global__ __launch_bounds__(256) void k_prep(
    const float* __restrict__ wv, const float* __restrict__ wf1,
    const float* __restrict__ wf3, const float* __restrict__ wf2,
    u16* __restrict__ WV, u16* __restrict__ WF1,
    u16* __restrict__ WF3, u16* __restrict__ WF2)
{
    int i = blockIdx.x * 256 + threadIdx.x;   // i = oc*256 + ic
    int oc = i >> 8, ic = i & 255;
    WV[i]  = f2b(wv[i]);
    WF1[i] = f2b(wf1[i]);
    WF3[i] = f2b(wf3[i]);
#pragma unroll
    for (int tap = 0; tap < 9; ++tap)
        WF2[oc * 2304 + tap * 256 + ic] = f2b(wf2[oc * 2304 + ic * 9 + tap]);
}

// ---------------- img -> channels-last bf16 ----------------
__global__ __launch_bounds__(256) void k_imgT(
    const float* __restrict__ img, u16* __restrict__ imgT)
{
    int b = blockIdx.z, pix0 = blockIdx.x * 32, ic0 = blockIdx.y * 32;
    int t = threadIdx.x;
    __shared__ float T[32][33];
    int ic = t >> 3, ps = (t & 7) * 4;
    f32x4 v = *(const f32x4*)&img[((size_t)b * C_ + ic0 + ic) * P_ + pix0 + ps];
    T[ic][ps] = v[0]; T[ic][ps + 1] = v[1]; T[ic][ps + 2] = v[2]; T[ic][ps + 3] = v[3];
    __syncthreads();
    int px = t >> 3, sg = (t & 7) * 4;
    u16 o0 = f2b(T[sg + 0][px]), o1 = f2b(T[sg + 1][px]);
    u16 o2 = f2b(T[sg + 2][px]), o3 = f2b(T[sg + 3][px]);
    uint2 val;
    val.x = (unsigned)o0 | ((unsigned)o1 << 16);
    val.y = (unsigned)o2 | ((unsigned)o3 << 16);
    *(uint2*)(imgT + ((size_t)b * P_ + pix0 + px) * C_ + ic0 + sg) = val;
}

// ---------------- language path (unchanged, fp32) ----------------
__global__ __launch_bounds__(256) void k_lang(
    const float* __restrict__ flang, const int* __restrict__ wmask,
    const float* __restrict__ W1, const float* __restrict__ b1,
    const float* __restrict__ W2, const float* __restrict__ b2,
    int* __restrict__ centers)
{
    int b = blockIdx.x, tid = threadIdx.x;
    __shared__ float inner[L_];
    __shared__ float cnt_s;
    __shared__ float favg[D_];
    __shared__ float hbuf[EMB_];
    __shared__ float mfs[16];

    if (tid == 0) {
        int total = 0;
        for (int l = 0; l < L_; ++l) total += wmask[b * L_ + l];
        int c = 0, cntv = 0;
        for (int l = 0; l < L_; ++l) {
            int m = wmask[b * L_ + l];
            c += m;
            float f = (m == 1 && c > 1 && c < total) ? 1.f : 0.f;
            inner[l] = f;
            cntv += (f != 0.f);
        }
        cnt_s = (float)cntv;
    }
    __syncthreads();
    float cinv = 1.f / cnt_s;
    for (int d = tid; d < D_; d += 256) {
        float s = 0.f;
        for (int l = 0; l < L_; ++l)
            s += flang[((size_t)b * L_ + l) * D_ + d] * inner[l];
        favg[d] = s * cinv;
    }
    __syncthreads();
    for (int e = tid; e < EMB_; e += 256) {
        float s = b1[e];
        const float* w = W1 + (size_t)e * D_;
        for (int d = 0; d < D_; ++d) s += w[d] * favg[d];
        hbuf[e] = s;
    }
    __syncthreads();
    if (tid < 16) {
        float s = b2[tid];
        const float* w = W2 + tid * EMB_;
        for (int d = 0; d < EMB_; ++d) s += w[d] * hbuf[d];
        mfs[tid] = 1.f / (1.f + expf(-s));
    }
    __syncthreads();
    if (tid < NC_) {
        centers[b * (NC_ * 2) + tid * 2 + 0] = (int)(mfs[tid * 2 + 0] * (float)HH);
        centers[b * (NC_ * 2) + tid * 2 + 1] = (int)(mfs[tid * 2 + 1] * (float)HH);
    }
}

// ---------------- gaussian -> gamma/beta maps (fp32) ----------------
__global__ __launch_bounds__(256) void k_gb(
    const int* __restrict__ centers,
    const float* __restrict__ wg, const float* __restrict__ sg, const float* __restrict__ bg,
    const float* __restrict__ wb, const float* __restrict__ sb, const float* __restrict__ bb,
    float* __restrict__ gmap, float* __restrict__ bmap)
{
    int idx = blockIdx.x * 256 + threadIdx.x;
    int b = idx >> 12;
    int p = idx & 4095;
    int gy = p >> 6, gx = p & 63;

    float w[NC_];
#pragma unroll
    for (int nc = 0; nc < NC_; ++nc) {
        int yc = centers[b * (NC_ * 2) + nc * 2 + 0];
        int xc = centers[b * (NC_ * 2) + nc * 2 + 1];
        int dy = gy - yc, dx = gx - xc;
        w[nc] = expf(-(float)(dy * dy + dx * dx) / 81.92f);
    }
    float gsum = 0.f, bmx = -1e30f;
#pragma unroll
    for (int c = 0; c < NC_; ++c) {
        float ag = 0.f, ab = 0.f;
#pragma unroll
        for (int ic = 0; ic < NC_; ++ic) {
            ag += wg[c * NC_ + ic] * w[ic];
            ab += wb[c * NC_ + ic] * w[ic];
        }
        gsum += tanhf(siluf(sg[c] * ag + bg[c]));
        bmx = fmaxf(bmx, tanhf(siluf(sb[c] * ab + bb[c])));
    }
    gmap[idx] = gsum * (1.f / (float)NC_);
    bmap[idx] = bmx;
}

// ---------------- MFMA GEMM helpers ----------------
// LDS row stride = 40 shorts (80 B): 16B-aligned rows, ~2-way bank aliasing (free).
static __device__ __forceinline__ void stage_W32(const u16* __restrict__ Wg, int Kst,
                                                 int k0, int t, short* sW)
{
    int ocb = t >> 2, sg = t & 3;
#pragma unroll
    for (int i = 0; i < 4; ++i) {
        int oc = ocb + i * 64;
        uint4 v = *(const uint4*)(Wg + (size_t)oc * Kst + k0 + sg * 8);
        *(uint4*)&sW[oc * 40 + sg * 8] = v;
    }
}
static __device__ __forceinline__ void stage_A32(const u16* __restrict__ Xb, int p0,
                                                 int k0, int t, short* sA)
{
    int pr = t >> 1, hf = t & 1;
    const u16* sp = Xb + (size_t)(p0 + pr) * C_ + k0 + hf * 16;
    uint4 v0 = *(const uint4*)sp;
    uint4 v1 = *(const uint4*)(sp + 8);
    *(uint4*)&sA[pr * 40 + hf * 16] = v0;
    *(uint4*)&sA[pr * 40 + hf * 16 + 8] = v1;
}
static __device__ __forceinline__ void frag_mfma(const short* sA, const short* sW,
                                                 int l15, int q, int w, f32x4 acc[8][4])
{
    bf16x8 a[8];
#pragma unroll
    for (int m = 0; m < 8; ++m)
        a[m] = *(const bf16x8*)&sA[(m * 16 + l15) * 40 + q * 8];
    bf16x8 bb[4];
#pragma unroll
    for (int n = 0; n < 4; ++n)
        bb[n] = *(const bf16x8*)&sW[(w * 64 + n * 16 + l15) * 40 + q * 8];
#pragma unroll
    for (int m = 0; m < 8; ++m)
#pragma unroll
        for (int n = 0; n < 4; ++n)
            acc[m][n] = __builtin_amdgcn_mfma_f32_16x16x32_bf16(a[m], bb[n], acc[m][n], 0, 0, 0);
}

// ---------------- visu conv + FiLM + l2norm -> v_film (bf16 CL) ----------------
__global__ __launch_bounds__(256) void k_visu(
    const u16* __restrict__ X, const u16* __restrict__ W,
    const float* __restrict__ s_visu, const float* __restrict__ b_visu,
    const float* __restrict__ gmap, const float* __restrict__ bmap,
    u16* __restrict__ Y)
{
    int b = blockIdx.y, p0 = blockIdx.x * 128, t = threadIdx.x;
    int l15 = t & 15, q = (t >> 4) & 3, w = t >> 6;
    __shared__ short sA[128 * 40];
    __shared__ short sW[256 * 40];
    __shared__ float red[4][128];
    __shared__ float invs[128];
    const u16* Xb = X + (size_t)b * CP_;

    f32x4 acc[8][4];
#pragma unroll
    for (int m = 0; m < 8; ++m)
#pragma unroll
        for (int n = 0; n < 4; ++n) acc[m][n] = (f32x4)0.f;

    for (int s = 0; s < 8; ++s) {
        stage_A32(Xb, p0, s * 32, t, sA);
        stage_W32(W, 256, s * 32, t, sW);
        __syncthreads();
        frag_mfma(sA, sW, l15, q, w, acc);
        __syncthreads();
    }

    float sc[4], sh[4];
#pragma unroll
    for (int n = 0; n < 4; ++n) {
        int oc = w * 64 + n * 16 + l15;
        sc[n] = s_visu[oc]; sh[n] = b_visu[oc];
    }
#pragma unroll
    for (int m = 0; m < 8; ++m) {
        f32x4 gv = *(const f32x4*)&gmap[(size_t)b * P_ + p0 + m * 16 + q * 4];
        f32x4 bm = *(const f32x4*)&bmap[(size_t)b * P_ + p0 + m * 16 + q * 4];
#pragma unroll
        for (int n = 0; n < 4; ++n)
#pragma unroll
            for (int r = 0; r < 4; ++r) {
                float y = sc[n] * acc[m][n][r] + sh[n];
                float mv = tanhf(siluf(y));
                acc[m][n][r] = gv[r] * mv + bm[r];
            }
    }
    // channel l2norm (over oc)
#pragma unroll
    for (int m = 0; m < 8; ++m)
#pragma unroll
        for (int r = 0; r < 4; ++r) {
            float ps = 0.f;
#pragma unroll
            for (int n = 0; n < 4; ++n) ps += acc[m][n][r] * acc[m][n][r];
            ps += __shfl_xor(ps, 1);
            ps += __shfl_xor(ps, 2);
            ps += __shfl_xor(ps, 4);
            ps += __shfl_xor(ps, 8);
            if (l15 == 0) red[w][m * 16 + q * 4 + r] = ps;
        }
    __syncthreads();
    if (t < 128) {
        float s = red[0][t] + red[1][t] + red[2][t] + red[3][t];
        invs[t] = 1.f / fmaxf(sqrtf(s), 1e-12f);
    }
    __syncthreads();

    u16* Yb = Y + (size_t)b * CP_ + (size_t)p0 * C_;
    short* LO = sA;   // reuse (5120 shorts >= 4096)
#pragma unroll 1
    for (int m = 0; m < 8; ++m) {
        __syncthreads();
#pragma unroll
        for (int n = 0; n < 4; ++n)
#pragma unroll
            for (int r = 0; r < 4; ++r) {
                float v = acc[m][n][r] * invs[m * 16 + q * 4 + r];
                LO[(q * 4 + r) * 256 + w * 64 + n * 16 + l15] = (short)f2b(v);
            }
        __syncthreads();
        int row = t >> 4, sg = t & 15;
        uint4 o0 = *(const uint4*)&LO[row * 256 + sg * 16];
        uint4 o1 = *(const uint4*)&LO[row * 256 + sg * 16 + 8];
        u16* dp = Yb + (size_t)(m * 16 + row) * C_ + sg * 16;
        *(uint4*)dp = o0;
        *(uint4*)(dp + 8) = o1;
    }
}

// ---------------- 1x1 conv (f1) + silu -> bf16 CL ----------------
__global__ __launch_bounds__(256) void k_f1(
    const u16* __restrict__ X, const u16* __restrict__ W,
    const float* __restrict__ scale, const float* __restrict__ shift,
    u16* __restrict__ Y)
{
    int b = blockIdx.y, p0 = blockIdx.x * 128, t = threadIdx.x;
    int l15 = t & 15, q = (t >> 4) & 3, w = t >> 6;
    __shared__ short sA[128 * 40];
    __shared__ short sW[256 * 40];
    const u16* Xb = X + (size_t)b * CP_;

    f32x4 acc[8][4];
#pragma unroll
    for (int m = 0; m < 8; ++m)
#pragma unroll
        for (int n = 0; n < 4; ++n) acc[m][n] = (f32x4)0.f;

    for (int s = 0; s < 8; ++s) {
        stage_A32(Xb, p0, s * 32, t, sA);
        stage_W32(W, 256, s * 32, t, sW);
        __syncthreads();
        frag_mfma(sA, sW, l15, q, w, acc);
        __syncthreads();
    }

    float sc[4], sh[4];
#pragma unroll
    for (int n = 0; n < 4; ++n) {
        int oc = w * 64 + n * 16 + l15;
        sc[n] = scale[oc]; sh[n] = shift[oc];
    }
    u16* Yb = Y + (size_t)b * CP_ + (size_t)p0 * C_;
    short* LO = sA;
#pragma unroll 1
    for (int m = 0; m < 8; ++m) {
        __syncthreads();
#pragma unroll
        for (int n = 0; n < 4; ++n)
#pragma unroll
            for (int r = 0; r < 4; ++r) {
                float v = siluf(sc[n] * acc[m][n][r] + sh[n]);
                LO[(q * 4 + r) * 256 + w * 64 + n * 16 + l15] = (short)f2b(v);
            }
        __syncthreads();
        int row = t >> 4, sg = t & 15;
        uint4 o0 = *(const uint4*)&LO[row * 256 + sg * 16];
        uint4 o1 = *(const uint4*)&LO[row * 256 + sg * 16 + 8];
        u16* dp = Yb + (size_t)(m * 16 + row) * C_ + sg * 16;
        *(uint4*)dp = o0;
        *(uint4*)(dp + 8) = o1;
    }
}

// ---------------- 3x3 conv (f2) + silu -> bf16 CL ----------------
__global__ __launch_bounds__(256) void k_f2(
    const u16* __restrict__ X, const u16* __restrict__ W,
    const float* __restrict__ scale, const float* __restrict__ shift,
    u16* __restrict__ Y)
{
    int b = blockIdx.y, p0 = blockIdx.x * 128, t = threadIdx.x;
    int l15 = t & 15, q = (t >> 4) & 3, w = t >> 6;
    __shared__ short sA[128 * 40];
    __shared__ short sW[256 * 40];
    const u16* Xb = X + (size_t)b * CP_;

    f32x4 acc[8][4];
#pragma unroll
    for (int m = 0; m < 8; ++m)
#pragma unroll
        for (int n = 0; n < 4; ++n) acc[m][n] = (f32x4)0.f;

    for (int s = 0; s < 72; ++s) {
        int k0 = s * 32;
        int tap = k0 >> 8;
        int icb = k0 & 255;
        int dy = tap / 3 - 1, dx = tap - (tap / 3) * 3 - 1;
        {
            int pr = t >> 1, hf = t & 1;
            int op = p0 + pr;
            int hs = (op >> 6) + dy, xs = (op & 63) + dx;
            uint4 v0 = make_uint4(0, 0, 0, 0), v1 = make_uint4(0, 0, 0, 0);
            if ((unsigned)hs < (unsigned)HH && (unsigned)xs < (unsigned)HH) {
                const u16* sp = Xb + (size_t)(hs * HH + xs) * C_ + icb + hf * 16;
                v0 = *(const uint4*)sp;
                v1 = *(const uint4*)(sp + 8);
            }
            *(uint4*)&sA[pr * 40 + hf * 16] = v0;
            *(uint4*)&sA[pr * 40 + hf * 16 + 8] = v1;
        }
        stage_W32(W, 2304, k0, t, sW);
        __syncthreads();
        frag_mfma(sA, sW, l15, q, w, acc);
        __syncthreads();
    }

    float sc[4], sh[4];
#pragma unroll
    for (int n = 0; n < 4; ++n) {
        int oc = w * 64 + n * 16 + l15;
        sc[n] = scale[oc]; sh[n] = shift[oc];
    }
    u16* Yb = Y + (size_t)b * CP_ + (size_t)p0 * C_;
    short* LO = sA;
#pragma unroll 1
    for (int m = 0; m < 8; ++m) {
        __syncthreads();
#pragma unroll
        for (int n = 0; n < 4; ++n)
#pragma unroll
            for (int r = 0; r < 4; ++r) {
                float v = siluf(sc[n] * acc[m][n][r] + sh[n]);
                LO[(q * 4 + r) * 256 + w * 64 + n * 16 + l15] = (short)f2b(v);
            }
        __syncthreads();
        int row = t >> 4, sg = t & 15;
        uint4 o0 = *(const uint4*)&LO[row * 256 + sg * 16];
        uint4 o1 = *(const uint4*)&LO[row * 256 + sg * 16 + 8];
        u16* dp = Yb + (size_t)(m * 16 + row) * C_ + sg * 16;
        *(uint4*)dp = o0;
        *(uint4*)(dp + 8) = o1;
    }
}

// ---------------- f3 conv + bias + v_add + l2norm -> out (fp32 CF) ----------------
__global__ __launch_bounds__(256) void k_final(
    const u16* __restrict__ X, const u16* __restrict__ W,
    const float* __restrict__ bias_f3, const float* __restrict__ img,
    const float* __restrict__ add_w, float* __restrict__ out)
{
    int b = blockIdx.y, p0 = blockIdx.x * 128, t = threadIdx.x;
    int l15 = t & 15, q = (t >> 4) & 3, w = t >> 6;
    __shared__ short sA[128 * 40];
    __shared__ short sW[256 * 40];
    __shared__ float red[4][128];
    __shared__ float invs[128];
    const u16* Xb = X + (size_t)b * CP_;

    f32x4 acc[8][4];
#pragma unroll
    for (int m = 0; m < 8; ++m)
#pragma unroll
        for (int n = 0; n < 4; ++n) acc[m][n] = (f32x4)0.f;

    for (int s = 0; s < 8; ++s) {
        stage_A32(Xb, p0, s * 32, t, sA);
        stage_W32(W, 256, s * 32, t, sW);
        __syncthreads();
        frag_mfma(sA, sW, l15, q, w, acc);
        __syncthreads();
    }

    float aw = tanhf(add_w[0]);
    float c1 = 1.f + aw, c2 = 1.f - aw;
    float bf[4];
#pragma unroll
    for (int n = 0; n < 4; ++n) bf[n] = bias_f3[w * 64 + n * 16 + l15];

#pragma unroll
    for (int m = 0; m < 8; ++m)
#pragma unroll
        for (int n = 0; n < 4; ++n) {
            int oc = w * 64 + n * 16 + l15;
            f32x4 iv = *(const f32x4*)&img[((size_t)b * C_ + oc) * P_ + p0 + m * 16 + q * 4];
#pragma unroll
            for (int r = 0; r < 4; ++r)
                acc[m][n][r] = c1 * iv[r] + c2 * (acc[m][n][r] + bf[n]);
        }
#pragma unroll
    for (int m = 0; m < 8; ++m)
#pragma unroll
        for (int r = 0; r < 4; ++r) {
            float ps = 0.f;
#pragma unroll
            for (int n = 0; n < 4; ++n) ps += acc[m][n][r] * acc[m][n][r];
            ps += __shfl_xor(ps, 1);
            ps += __shfl_xor(ps, 2);
            ps += __shfl_xor(ps, 4);
            ps += __shfl_xor(ps, 8);
            if (l15 == 0) red[w][m * 16 + q * 4 + r] = ps;
        }
    __syncthreads();
    if (t < 128) {
        float s = red[0][t] + red[1][t] + red[2][t] + red[3][t];
        invs[t] = 1.f / fmaxf(sqrtf(s), 1e-12f);
    }
    __syncthreads();
#pragma unroll
    for (int m = 0; m < 8; ++m) {
        f32x4 iv = *(const f32x4*)&invs[m * 16 + q * 4];
#pragma unroll
        for (int n = 0; n < 4; ++n) {
            int oc = w * 64 + n * 16 + l15;
            f32x4 o;
#pragma unroll
            for (int r = 0; r < 4; ++r) o[r] = acc[m][n][r] * iv[r];
            *(f32x4*)&out[((size_t)b * C_ + oc) * P_ + p0 + m * 16 + q * 4] = o;
        }
    }
}

extern "C" void kernel_launch(void* const* d_in, const int* in_sizes, int n_in,
                              void* d_out, int out_size, void* d_ws, size_t ws_size,
                              hipStream_t stream)
{
    const float* img     = (const float*)d_in[0];
    const float* flang   = (const float*)d_in[1];
    const int*   wmask   = (const int*)d_in[2];
    const float* w_visu  = (const float*)d_in[3];
    const float* s_visu  = (const float*)d_in[4];
    const float* b_visu  = (const float*)d_in[5];
    const float* w_g     = (const float*)d_in[6];
    const float* s_g     = (const float*)d_in[7];
    const float* b_g     = (const float*)d_in[8];
    const float* w_b     = (const float*)d_in[9];
    const float* s_b     = (const float*)d_in[10];
    const float* b_b     = (const float*)d_in[11];
    const float* W1      = (const float*)d_in[12];
    const float* b1      = (const float*)d_in[13];
    const float* W2      = (const float*)d_in[14];
    const float* b2      = (const float*)d_in[15];
    const float* w_f1    = (const float*)d_in[16];
    const float* s_f1    = (const float*)d_in[17];
    const float* b_f1    = (const float*)d_in[18];
    const float* w_f2    = (const float*)d_in[19];
    const float* s_f2    = (const float*)d_in[20];
    const float* b_f2    = (const float*)d_in[21];
    const float* w_f3    = (const float*)d_in[22];
    const float* bias_f3 = (const float*)d_in[23];
    const float* add_w   = (const float*)d_in[24];

    float* out = (float*)d_out;

    // workspace layout (u16 elements)
    u16* bigA = (u16*)d_ws;                 // 33554432: v_film, then v2
    u16* bigB = bigA + (size_t)B_ * CP_;    // 33554432: imgT, then v
    u16* WV   = bigB + (size_t)B_ * CP_;    // 65536
    u16* WF1  = WV + 65536;                 // 65536
    u16* WF3  = WF1 + 65536;                // 65536
    u16* WF2  = WF3 + 65536;                // 589824
    float* gmap = (float*)(WF2 + 589824);   // 131072 f32
    float* bmap = gmap + (size_t)B_ * P_;   // 131072 f32
    int* centers = (int*)(bmap + (size_t)B_ * P_);

    k_prep<<<256, 256, 0, stream>>>(w_visu, w_f1, w_f3, w_f2, WV, WF1, WF3, WF2);
    k_lang<<<B_, 256, 0, stream>>>(flang, wmask, W1, b1, W2, b2, centers);
    k_gb<<<(B_ * P_) / 256, 256, 0, stream>>>(centers, w_g, s_g, b_g, w_b, s_b, b_b, gmap, bmap);
    k_imgT<<<dim3(P_ / 32, C_ / 32, B_), 256, 0, stream>>>(img, bigB);
    k_visu<<<dim3(P_ / 128, B_), 256, 0, stream>>>(bigB, WV, s_visu, b_visu, gmap, bmap, bigA);
    k_f1<<<dim3(P_ / 128, B_), 256, 0, stream>>>(bigA, WF1, s_f1, b_f1, bigB);
    k_f2<<<dim3(P_ / 128, B_), 256, 0, stream>>>(bigB, WF2, s_f2, b_f2, bigA);
    k_final<<<dim3(P_ / 128, B_), 256, 0, stream>>>(bigA, WF3, bias_f3, img, add_w, out);
}

// Round 3
// 2323.387 us; speedup vs baseline: 1.3817x; 1.0013x over previous
//
#include <hip/hip_runtime.h>
#include <hip/hip_bf16.h>

#define B_   32
#define C_   256
#define HH   64
#define P_   4096   // 64*64
#define L_   40
#define D_   768
#define NC_  8
#define EMB_ 392
#define CP_  (C_*P_)   // 1048576

typedef __attribute__((ext_vector_type(8))) short bf16x8;
typedef __attribute__((ext_vector_type(4))) float f32x4;
typedef unsigned short u16;

static __device__ __forceinline__ float siluf(float y) {
    return y / (1.f + expf(-y));
}
static __device__ __forceinline__ u16 f2b(float f) {
    __hip_bfloat16 h = __float2bfloat16(f);
    return *reinterpret_cast<u16*>(&h);
}

// ---------------- weight pack to bf16 ----------------
// WV/WF1/WF3: [oc][ic] ; WF2: [oc][tap*256+ic]  (K-contiguous rows)
__global__ __launch_bounds__(256) void k_prep(
    const float* __restrict__ wv, const float* __restrict__ wf1,
    const float* __restrict__ wf3, const float* __restrict__ wf2,
    u16* __restrict__ WV, u16* __restrict__ WF1,
    u16* __restrict__ WF3, u16* __restrict__ WF2)
{
    int i = blockIdx.x * 256 + threadIdx.x;   // i = oc*256 + ic
    int oc = i >> 8, ic = i & 255;
    WV[i]  = f2b(wv[i]);
    WF1[i] = f2b(wf1[i]);
    WF3[i] = f2b(wf3[i]);
#pragma unroll
    for (int tap = 0; tap < 9; ++tap)
        WF2[oc * 2304 + tap * 256 + ic] = f2b(wf2[oc * 2304 + ic * 9 + tap]);
}

// ---------------- img -> channels-last bf16 ----------------
__global__ __launch_bounds__(256) void k_imgT(
    const float* __restrict__ img, u16* __restrict__ imgT)
{
    int b = blockIdx.z, pix0 = blockIdx.x * 32, ic0 = blockIdx.y * 32;
    int t = threadIdx.x;
    __shared__ float T[32][33];
    int ic = t >> 3, ps = (t & 7) * 4;
    f32x4 v = *(const f32x4*)&img[((size_t)b * C_ + ic0 + ic) * P_ + pix0 + ps];
    T[ic][ps] = v[0]; T[ic][ps + 1] = v[1]; T[ic][ps + 2] = v[2]; T[ic][ps + 3] = v[3];
    __syncthreads();
    int px = t >> 3, sg = (t & 7) * 4;
    u16 o0 = f2b(T[sg + 0][px]), o1 = f2b(T[sg + 1][px]);
    u16 o2 = f2b(T[sg + 2][px]), o3 = f2b(T[sg + 3][px]);
    uint2 val;
    val.x = (unsigned)o0 | ((unsigned)o1 << 16);
    val.y = (unsigned)o2 | ((unsigned)o3 << 16);
    *(uint2*)(imgT + ((size_t)b * P_ + pix0 + px) * C_ + ic0 + sg) = val;
}

// ---------------- language path (fp32) ----------------
__global__ __launch_bounds__(256) void k_lang(
    const float* __restrict__ flang, const int* __restrict__ wmask,
    const float* __restrict__ W1, const float* __restrict__ b1,
    const float* __restrict__ W2, const float* __restrict__ b2,
    int* __restrict__ centers)
{
    int b = blockIdx.x, tid = threadIdx.x;
    __shared__ float inner[L_];
    __shared__ float cnt_s;
    __shared__ float favg[D_];
    __shared__ float hbuf[EMB_];
    __shared__ float mfs[16];

    if (tid == 0) {
        int total = 0;
        for (int l = 0; l < L_; ++l) total += wmask[b * L_ + l];
        int c = 0, cntv = 0;
        for (int l = 0; l < L_; ++l) {
            int m = wmask[b * L_ + l];
            c += m;
            float f = (m == 1 && c > 1 && c < total) ? 1.f : 0.f;
            inner[l] = f;
            cntv += (f != 0.f);
        }
        cnt_s = (float)cntv;
    }
    __syncthreads();
    float cinv = 1.f / cnt_s;
    for (int d = tid; d < D_; d += 256) {
        float s = 0.f;
        for (int l = 0; l < L_; ++l)
            s += flang[((size_t)b * L_ + l) * D_ + d] * inner[l];
        favg[d] = s * cinv;
    }
    __syncthreads();
    for (int e = tid; e < EMB_; e += 256) {
        float s = b1[e];
        const float* w = W1 + (size_t)e * D_;
        for (int d = 0; d < D_; ++d) s += w[d] * favg[d];
        hbuf[e] = s;
    }
    __syncthreads();
    if (tid < 16) {
        float s = b2[tid];
        const float* w = W2 + tid * EMB_;
        for (int d = 0; d < EMB_; ++d) s += w[d] * hbuf[d];
        mfs[tid] = 1.f / (1.f + expf(-s));
    }
    __syncthreads();
    if (tid < NC_) {
        centers[b * (NC_ * 2) + tid * 2 + 0] = (int)(mfs[tid * 2 + 0] * (float)HH);
        centers[b * (NC_ * 2) + tid * 2 + 1] = (int)(mfs[tid * 2 + 1] * (float)HH);
    }
}

// ---------------- gaussian -> gamma/beta maps (fp32) ----------------
__global__ __launch_bounds__(256) void k_gb(
    const int* __restrict__ centers,
    const float* __restrict__ wg, const float* __restrict__ sg, const float* __restrict__ bg,
    const float* __restrict__ wb, const float* __restrict__ sb, const float* __restrict__ bb,
    float* __restrict__ gmap, float* __restrict__ bmap)
{
    int idx = blockIdx.x * 256 + threadIdx.x;
    int b = idx >> 12;
    int p = idx & 4095;
    int gy = p >> 6, gx = p & 63;

    float w[NC_];
#pragma unroll
    for (int nc = 0; nc < NC_; ++nc) {
        int yc = centers[b * (NC_ * 2) + nc * 2 + 0];
        int xc = centers[b * (NC_ * 2) + nc * 2 + 1];
        int dy = gy - yc, dx = gx - xc;
        w[nc] = expf(-(float)(dy * dy + dx * dx) / 81.92f);
    }
    float gsum = 0.f, bmx = -1e30f;
#pragma unroll
    for (int c = 0; c < NC_; ++c) {
        float ag = 0.f, ab = 0.f;
#pragma unroll
        for (int ic = 0; ic < NC_; ++ic) {
            ag += wg[c * NC_ + ic] * w[ic];
            ab += wb[c * NC_ + ic] * w[ic];
        }
        gsum += tanhf(siluf(sg[c] * ag + bg[c]));
        bmx = fmaxf(bmx, tanhf(siluf(sb[c] * ab + bb[c])));
    }
    gmap[idx] = gsum * (1.f / (float)NC_);
    bmap[idx] = bmx;
}

// ---------------- MFMA GEMM helpers ----------------
// LDS row stride = 40 shorts (80 B): 16B-aligned rows, ~2-way bank aliasing (free).
static __device__ __forceinline__ void stage_W32(const u16* __restrict__ Wg, int Kst,
                                                 int k0, int t, short* sW)
{
    int ocb = t >> 2, sg = t & 3;
#pragma unroll
    for (int i = 0; i < 4; ++i) {
        int oc = ocb + i * 64;
        uint4 v = *(const uint4*)(Wg + (size_t)oc * Kst + k0 + sg * 8);
        *(uint4*)&sW[oc * 40 + sg * 8] = v;
    }
}
static __device__ __forceinline__ void stage_A32(const u16* __restrict__ Xb, int p0,
                                                 int k0, int t, short* sA)
{
    int pr = t >> 1, hf = t & 1;
    const u16* sp = Xb + (size_t)(p0 + pr) * C_ + k0 + hf * 16;
    uint4 v0 = *(const uint4*)sp;
    uint4 v1 = *(const uint4*)(sp + 8);
    *(uint4*)&sA[pr * 40 + hf * 16] = v0;
    *(uint4*)&sA[pr * 40 + hf * 16 + 8] = v1;
}
static __device__ __forceinline__ void frag_mfma(const short* sA, const short* sW,
                                                 int l15, int q, int w, f32x4 acc[8][4])
{
    bf16x8 a[8];
#pragma unroll
    for (int m = 0; m < 8; ++m)
        a[m] = *(const bf16x8*)&sA[(m * 16 + l15) * 40 + q * 8];
    bf16x8 bb[4];
#pragma unroll
    for (int n = 0; n < 4; ++n)
        bb[n] = *(const bf16x8*)&sW[(w * 64 + n * 16 + l15) * 40 + q * 8];
#pragma unroll
    for (int m = 0; m < 8; ++m)
#pragma unroll
        for (int n = 0; n < 4; ++n)
            acc[m][n] = __builtin_amdgcn_mfma_f32_16x16x32_bf16(a[m], bb[n], acc[m][n], 0, 0, 0);
}

// ---------------- visu conv + FiLM + l2norm -> v_film (bf16 CL) ----------------
__global__ __launch_bounds__(256, 1) void k_visu(
    const u16* __restrict__ X, const u16* __restrict__ W,
    const float* __restrict__ s_visu, const float* __restrict__ b_visu,
    const float* __restrict__ gmap, const float* __restrict__ bmap,
    u16* __restrict__ Y)
{
    int b = blockIdx.y, p0 = blockIdx.x * 128, t = threadIdx.x;
    int l15 = t & 15, q = (t >> 4) & 3, w = t >> 6;
    __shared__ short sA[128 * 40];
    __shared__ short sW[256 * 40];
    __shared__ float red[4][128];
    __shared__ float invs[128];
    const u16* Xb = X + (size_t)b * CP_;

    f32x4 acc[8][4];
#pragma unroll
    for (int m = 0; m < 8; ++m)
#pragma unroll
        for (int n = 0; n < 4; ++n) acc[m][n] = (f32x4)0.f;

    for (int s = 0; s < 8; ++s) {
        stage_A32(Xb, p0, s * 32, t, sA);
        stage_W32(W, 256, s * 32, t, sW);
        __syncthreads();
        frag_mfma(sA, sW, l15, q, w, acc);
        __syncthreads();
    }

    float sc[4], sh[4];
#pragma unroll
    for (int n = 0; n < 4; ++n) {
        int oc = w * 64 + n * 16 + l15;
        sc[n] = s_visu[oc]; sh[n] = b_visu[oc];
    }
#pragma unroll
    for (int m = 0; m < 8; ++m) {
        f32x4 gv = *(const f32x4*)&gmap[(size_t)b * P_ + p0 + m * 16 + q * 4];
        f32x4 bm = *(const f32x4*)&bmap[(size_t)b * P_ + p0 + m * 16 + q * 4];
#pragma unroll
        for (int n = 0; n < 4; ++n)
#pragma unroll
            for (int r = 0; r < 4; ++r) {
                float y = sc[n] * acc[m][n][r] + sh[n];
                float mv = tanhf(siluf(y));
                acc[m][n][r] = gv[r] * mv + bm[r];
            }
    }
    // channel l2norm (over oc)
#pragma unroll
    for (int m = 0; m < 8; ++m)
#pragma unroll
        for (int r = 0; r < 4; ++r) {
            float ps = 0.f;
#pragma unroll
            for (int n = 0; n < 4; ++n) ps += acc[m][n][r] * acc[m][n][r];
            ps += __shfl_xor(ps, 1);
            ps += __shfl_xor(ps, 2);
            ps += __shfl_xor(ps, 4);
            ps += __shfl_xor(ps, 8);
            if (l15 == 0) red[w][m * 16 + q * 4 + r] = ps;
        }
    __syncthreads();
    if (t < 128) {
        float s = red[0][t] + red[1][t] + red[2][t] + red[3][t];
        invs[t] = 1.f / fmaxf(sqrtf(s), 1e-12f);
    }
    __syncthreads();

    u16* Yb = Y + (size_t)b * CP_ + (size_t)p0 * C_;
    short* LO = sA;   // reuse (5120 shorts >= 4096)
#pragma unroll 1
    for (int m = 0; m < 8; ++m) {
        __syncthreads();
#pragma unroll
        for (int n = 0; n < 4; ++n)
#pragma unroll
            for (int r = 0; r < 4; ++r) {
                float v = acc[m][n][r] * invs[m * 16 + q * 4 + r];
                LO[(q * 4 + r) * 256 + w * 64 + n * 16 + l15] = (short)f2b(v);
            }
        __syncthreads();
        int row = t >> 4, sg = t & 15;
        uint4 o0 = *(const uint4*)&LO[row * 256 + sg * 16];
        uint4 o1 = *(const uint4*)&LO[row * 256 + sg * 16 + 8];
        u16* dp = Yb + (size_t)(m * 16 + row) * C_ + sg * 16;
        *(uint4*)dp = o0;
        *(uint4*)(dp + 8) = o1;
    }
}

// ---------------- 1x1 conv (f1) + silu -> bf16 CL ----------------
__global__ __launch_bounds__(256, 1) void k_f1(
    const u16* __restrict__ X, const u16* __restrict__ W,
    const float* __restrict__ scale, const float* __restrict__ shift,
    u16* __restrict__ Y)
{
    int b = blockIdx.y, p0 = blockIdx.x * 128, t = threadIdx.x;
    int l15 = t & 15, q = (t >> 4) & 3, w = t >> 6;
    __shared__ short sA[128 * 40];
    __shared__ short sW[256 * 40];
    const u16* Xb = X + (size_t)b * CP_;

    f32x4 acc[8][4];
#pragma unroll
    for (int m = 0; m < 8; ++m)
#pragma unroll
        for (int n = 0; n < 4; ++n) acc[m][n] = (f32x4)0.f;

    for (int s = 0; s < 8; ++s) {
        stage_A32(Xb, p0, s * 32, t, sA);
        stage_W32(W, 256, s * 32, t, sW);
        __syncthreads();
        frag_mfma(sA, sW, l15, q, w, acc);
        __syncthreads();
    }

    float sc[4], sh[4];
#pragma unroll
    for (int n = 0; n < 4; ++n) {
        int oc = w * 64 + n * 16 + l15;
        sc[n] = scale[oc]; sh[n] = shift[oc];
    }
    u16* Yb = Y + (size_t)b * CP_ + (size_t)p0 * C_;
    short* LO = sA;
#pragma unroll 1
    for (int m = 0; m < 8; ++m) {
        __syncthreads();
#pragma unroll
        for (int n = 0; n < 4; ++n)
#pragma unroll
            for (int r = 0; r < 4; ++r) {
                float v = siluf(sc[n] * acc[m][n][r] + sh[n]);
                LO[(q * 4 + r) * 256 + w * 64 + n * 16 + l15] = (short)f2b(v);
            }
        __syncthreads();
        int row = t >> 4, sg = t & 15;
        uint4 o0 = *(const uint4*)&LO[row * 256 + sg * 16];
        uint4 o1 = *(const uint4*)&LO[row * 256 + sg * 16 + 8];
        u16* dp = Yb + (size_t)(m * 16 + row) * C_ + sg * 16;
        *(uint4*)dp = o0;
        *(uint4*)(dp + 8) = o1;
    }
}

// ---------------- 3x3 conv (f2) + silu -> bf16 CL ----------------
__global__ __launch_bounds__(256, 1) void k_f2(
    const u16* __restrict__ X, const u16* __restrict__ W,
    const float* __restrict__ scale, const float* __restrict__ shift,
    u16* __restrict__ Y)
{
    int b = blockIdx.y, p0 = blockIdx.x * 128, t = threadIdx.x;
    int l15 = t & 15, q = (t >> 4) & 3, w = t >> 6;
    __shared__ short sA[128 * 40];
    __shared__ short sW[256 * 40];
    const u16* Xb = X + (size_t)b * CP_;

    f32x4 acc[8][4];
#pragma unroll
    for (int m = 0; m < 8; ++m)
#pragma unroll
        for (int n = 0; n < 4; ++n) acc[m][n] = (f32x4)0.f;

    for (int s = 0; s < 72; ++s) {
        int k0 = s * 32;
        int tap = k0 >> 8;
        int icb = k0 & 255;
        int dy = tap / 3 - 1, dx = tap - (tap / 3) * 3 - 1;
        {
            int pr = t >> 1, hf = t & 1;
            int op = p0 + pr;
            int hs = (op >> 6) + dy, xs = (op & 63) + dx;
            uint4 v0 = make_uint4(0, 0, 0, 0), v1 = make_uint4(0, 0, 0, 0);
            if ((unsigned)hs < (unsigned)HH && (unsigned)xs < (unsigned)HH) {
                const u16* sp = Xb + (size_t)(hs * HH + xs) * C_ + icb + hf * 16;
                v0 = *(const uint4*)sp;
                v1 = *(const uint4*)(sp + 8);
            }
            *(uint4*)&sA[pr * 40 + hf * 16] = v0;
            *(uint4*)&sA[pr * 40 + hf * 16 + 8] = v1;
        }
        stage_W32(W, 2304, k0, t, sW);
        __syncthreads();
        frag_mfma(sA, sW, l15, q, w, acc);
        __syncthreads();
    }

    float sc[4], sh[4];
#pragma unroll
    for (int n = 0; n < 4; ++n) {
        int oc = w * 64 + n * 16 + l15;
        sc[n] = scale[oc]; sh[n] = shift[oc];
    }
    u16* Yb = Y + (size_t)b * CP_ + (size_t)p0 * C_;
    short* LO = sA;
#pragma unroll 1
    for (int m = 0; m < 8; ++m) {
        __syncthreads();
#pragma unroll
        for (int n = 0; n < 4; ++n)
#pragma unroll
            for (int r = 0; r < 4; ++r) {
                float v = siluf(sc[n] * acc[m][n][r] + sh[n]);
                LO[(q * 4 + r) * 256 + w * 64 + n * 16 + l15] = (short)f2b(v);
            }
        __syncthreads();
        int row = t >> 4, sg = t & 15;
        uint4 o0 = *(const uint4*)&LO[row * 256 + sg * 16];
        uint4 o1 = *(const uint4*)&LO[row * 256 + sg * 16 + 8];
        u16* dp = Yb + (size_t)(m * 16 + row) * C_ + sg * 16;
        *(uint4*)dp = o0;
        *(uint4*)(dp + 8) = o1;
    }
}

// ---------------- f3 conv + bias + v_add + l2norm -> out (fp32 CF) ----------------
__global__ __launch_bounds__(256, 1) void k_final(
    const u16* __restrict__ X, const u16* __restrict__ W,
    const float* __restrict__ bias_f3, const float* __restrict__ img,
    const float* __restrict__ add_w, float* __restrict__ out)
{
    int b = blockIdx.y, p0 = blockIdx.x * 128, t = threadIdx.x;
    int l15 = t & 15, q = (t >> 4) & 3, w = t >> 6;
    __shared__ short sA[128 * 40];
    __shared__ short sW[256 * 40];
    __shared__ float red[4][128];
    __shared__ float invs[128];
    const u16* Xb = X + (size_t)b * CP_;

    f32x4 acc[8][4];
#pragma unroll
    for (int m = 0; m < 8; ++m)
#pragma unroll
        for (int n = 0; n < 4; ++n) acc[m][n] = (f32x4)0.f;

    for (int s = 0; s < 8; ++s) {
        stage_A32(Xb, p0, s * 32, t, sA);
        stage_W32(W, 256, s * 32, t, sW);
        __syncthreads();
        frag_mfma(sA, sW, l15, q, w, acc);
        __syncthreads();
    }

    float aw = tanhf(add_w[0]);
    float c1 = 1.f + aw, c2 = 1.f - aw;
    float bf[4];
#pragma unroll
    for (int n = 0; n < 4; ++n) bf[n] = bias_f3[w * 64 + n * 16 + l15];

#pragma unroll
    for (int m = 0; m < 8; ++m)
#pragma unroll
        for (int n = 0; n < 4; ++n) {
            int oc = w * 64 + n * 16 + l15;
            f32x4 iv = *(const f32x4*)&img[((size_t)b * C_ + oc) * P_ + p0 + m * 16 + q * 4];
#pragma unroll
            for (int r = 0; r < 4; ++r)
                acc[m][n][r] = c1 * iv[r] + c2 * (acc[m][n][r] + bf[n]);
        }
#pragma unroll
    for (int m = 0; m < 8; ++m)
#pragma unroll
        for (int r = 0; r < 4; ++r) {
            float ps = 0.f;
#pragma unroll
            for (int n = 0; n < 4; ++n) ps += acc[m][n][r] * acc[m][n][r];
            ps += __shfl_xor(ps, 1);
            ps += __shfl_xor(ps, 2);
            ps += __shfl_xor(ps, 4);
            ps += __shfl_xor(ps, 8);
            if (l15 == 0) red[w][m * 16 + q * 4 + r] = ps;
        }
    __syncthreads();
    if (t < 128) {
        float s = red[0][t] + red[1][t] + red[2][t] + red[3][t];
        invs[t] = 1.f / fmaxf(sqrtf(s), 1e-12f);
    }
    __syncthreads();
#pragma unroll
    for (int m = 0; m < 8; ++m) {
        f32x4 iv = *(const f32x4*)&invs[m * 16 + q * 4];
#pragma unroll
        for (int n = 0; n < 4; ++n) {
            int oc = w * 64 + n * 16 + l15;
            f32x4 o;
#pragma unroll
            for (int r = 0; r < 4; ++r) o[r] = acc[m][n][r] * iv[r];
            *(f32x4*)&out[((size_t)b * C_ + oc) * P_ + p0 + m * 16 + q * 4] = o;
        }
    }
}

extern "C" void kernel_launch(void* const* d_in, const int* in_sizes, int n_in,
                              void* d_out, int out_size, void* d_ws, size_t ws_size,
                              hipStream_t stream)
{
    const float* img     = (const float*)d_in[0];
    const float* flang   = (const float*)d_in[1];
    const int*   wmask   = (const int*)d_in[2];
    const float* w_visu  = (const float*)d_in[3];
    const float* s_visu  = (const float*)d_in[4];
    const float* b_visu  = (const float*)d_in[5];
    const float* w_g     = (const float*)d_in[6];
    const float* s_g     = (const float*)d_in[7];
    const float* b_g     = (const float*)d_in[8];
    const float* w_b     = (const float*)d_in[9];
    const float* s_b     = (const float*)d_in[10];
    const float* b_b     = (const float*)d_in[11];
    const float* W1      = (const float*)d_in[12];
    const float* b1      = (const float*)d_in[13];
    const float* W2      = (const float*)d_in[14];
    const float* b2      = (const float*)d_in[15];
    const float* w_f1    = (const float*)d_in[16];
    const float* s_f1    = (const float*)d_in[17];
    const float* b_f1    = (const float*)d_in[18];
    const float* w_f2    = (const float*)d_in[19];
    const float* s_f2    = (const float*)d_in[20];
    const float* b_f2    = (const float*)d_in[21];
    const float* w_f3    = (const float*)d_in[22];
    const float* bias_f3 = (const float*)d_in[23];
    const float* add_w   = (const float*)d_in[24];

    float* out = (float*)d_out;

    // workspace layout (u16 elements)
    u16* bigA = (u16*)d_ws;                 // 33554432: v_film, then v2
    u16* bigB = bigA + (size_t)B_ * CP_;    // 33554432: imgT, then v
    u16* WV   = bigB + (size_t)B_ * CP_;    // 65536
    u16* WF1  = WV + 65536;                 // 65536
    u16* WF3  = WF1 + 65536;                // 65536
    u16* WF2  = WF3 + 65536;                // 589824
    float* gmap = (float*)(WF2 + 589824);   // 131072 f32
    float* bmap = gmap + (size_t)B_ * P_;   // 131072 f32
    int* centers = (int*)(bmap + (size_t)B_ * P_);

    k_prep<<<256, 256, 0, stream>>>(w_visu, w_f1, w_f3, w_f2, WV, WF1, WF3, WF2);
    k_lang<<<B_, 256, 0, stream>>>(flang, wmask, W1, b1, W2, b2, centers);
    k_gb<<<(B_ * P_) / 256, 256, 0, stream>>>(centers, w_g, s_g, b_g, w_b, s_b, b_b, gmap, bmap);
    k_imgT<<<dim3(P_ / 32, C_ / 32, B_), 256, 0, stream>>>(img, bigB);
    k_visu<<<dim3(P_ / 128, B_), 256, 0, stream>>>(bigB, WV, s_visu, b_visu, gmap, bmap, bigA);
    k_f1<<<dim3(P_ / 128, B_), 256, 0, stream>>>(bigA, WF1, s_f1, b_f1, bigB);
    k_f2<<<dim3(P_ / 128, B_), 256, 0, stream>>>(bigB, WF2, s_f2, b_f2, bigA);
    k_final<<<dim3(P_ / 128, B_), 256, 0, stream>>>(bigA, WF3, bias_f3, img, add_w, out);
}

// Round 4
// 807.750 us; speedup vs baseline: 3.9743x; 2.8764x over previous
//
#include <hip/hip_runtime.h>
#include <hip/hip_bf16.h>

#define B_   32
#define C_   256
#define HH   64
#define P_   4096   // 64*64
#define L_   40
#define D_   768
#define NC_  8
#define EMB_ 392
#define CP_  (C_*P_)   // 1048576

typedef __attribute__((ext_vector_type(8))) short bf16x8;
typedef __attribute__((ext_vector_type(4))) float f32x4;
typedef unsigned short u16;

static __device__ __forceinline__ float siluf(float y) {
    return y / (1.f + expf(-y));
}
static __device__ __forceinline__ u16 f2b(float f) {
    __hip_bfloat16 h = __float2bfloat16(f);
    return *reinterpret_cast<u16*>(&h);
}

// ---------------- weight pack to bf16 ----------------
// WV/WF1/WF3: [oc][ic] ; WF2: [oc][tap*256+ic]  (K-contiguous rows)
__global__ __launch_bounds__(256) void k_prep(
    const float* __restrict__ wv, const float* __restrict__ wf1,
    const float* __restrict__ wf3, const float* __restrict__ wf2,
    u16* __restrict__ WV, u16* __restrict__ WF1,
    u16* __restrict__ WF3, u16* __restrict__ WF2)
{
    int i = blockIdx.x * 256 + threadIdx.x;   // i = oc*256 + ic
    int oc = i >> 8, ic = i & 255;
    WV[i]  = f2b(wv[i]);
    WF1[i] = f2b(wf1[i]);
    WF3[i] = f2b(wf3[i]);
#pragma unroll
    for (int tap = 0; tap < 9; ++tap)
        WF2[oc * 2304 + tap * 256 + ic] = f2b(wf2[oc * 2304 + ic * 9 + tap]);
}

// ---------------- img -> channels-last bf16 ----------------
__global__ __launch_bounds__(256) void k_imgT(
    const float* __restrict__ img, u16* __restrict__ imgT)
{
    int b = blockIdx.z, pix0 = blockIdx.x * 32, ic0 = blockIdx.y * 32;
    int t = threadIdx.x;
    __shared__ float T[32][33];
    int ic = t >> 3, ps = (t & 7) * 4;
    f32x4 v = *(const f32x4*)&img[((size_t)b * C_ + ic0 + ic) * P_ + pix0 + ps];
    T[ic][ps] = v[0]; T[ic][ps + 1] = v[1]; T[ic][ps + 2] = v[2]; T[ic][ps + 3] = v[3];
    __syncthreads();
    int px = t >> 3, sg = (t & 7) * 4;
    u16 o0 = f2b(T[sg + 0][px]), o1 = f2b(T[sg + 1][px]);
    u16 o2 = f2b(T[sg + 2][px]), o3 = f2b(T[sg + 3][px]);
    uint2 val;
    val.x = (unsigned)o0 | ((unsigned)o1 << 16);
    val.y = (unsigned)o2 | ((unsigned)o3 << 16);
    *(uint2*)(imgT + ((size_t)b * P_ + pix0 + px) * C_ + ic0 + sg) = val;
}

// ---------------- language path (fp32) ----------------
__global__ __launch_bounds__(256) void k_lang(
    const float* __restrict__ flang, const int* __restrict__ wmask,
    const float* __restrict__ W1, const float* __restrict__ b1,
    const float* __restrict__ W2, const float* __restrict__ b2,
    int* __restrict__ centers)
{
    int b = blockIdx.x, tid = threadIdx.x;
    __shared__ float inner[L_];
    __shared__ float cnt_s;
    __shared__ float favg[D_];
    __shared__ float hbuf[EMB_];
    __shared__ float mfs[16];

    if (tid == 0) {
        int total = 0;
        for (int l = 0; l < L_; ++l) total += wmask[b * L_ + l];
        int c = 0, cntv = 0;
        for (int l = 0; l < L_; ++l) {
            int m = wmask[b * L_ + l];
            c += m;
            float f = (m == 1 && c > 1 && c < total) ? 1.f : 0.f;
            inner[l] = f;
            cntv += (f != 0.f);
        }
        cnt_s = (float)cntv;
    }
    __syncthreads();
    float cinv = 1.f / cnt_s;
    for (int d = tid; d < D_; d += 256) {
        float s = 0.f;
        for (int l = 0; l < L_; ++l)
            s += flang[((size_t)b * L_ + l) * D_ + d] * inner[l];
        favg[d] = s * cinv;
    }
    __syncthreads();
    for (int e = tid; e < EMB_; e += 256) {
        float s = b1[e];
        const float* w = W1 + (size_t)e * D_;
        for (int d = 0; d < D_; ++d) s += w[d] * favg[d];
        hbuf[e] = s;
    }
    __syncthreads();
    if (tid < 16) {
        float s = b2[tid];
        const float* w = W2 + tid * EMB_;
        for (int d = 0; d < EMB_; ++d) s += w[d] * hbuf[d];
        mfs[tid] = 1.f / (1.f + expf(-s));
    }
    __syncthreads();
    if (tid < NC_) {
        centers[b * (NC_ * 2) + tid * 2 + 0] = (int)(mfs[tid * 2 + 0] * (float)HH);
        centers[b * (NC_ * 2) + tid * 2 + 1] = (int)(mfs[tid * 2 + 1] * (float)HH);
    }
}

// ---------------- gaussian -> gamma/beta maps (fp32) ----------------
__global__ __launch_bounds__(256) void k_gb(
    const int* __restrict__ centers,
    const float* __restrict__ wg, const float* __restrict__ sg, const float* __restrict__ bg,
    const float* __restrict__ wb, const float* __restrict__ sb, const float* __restrict__ bb,
    float* __restrict__ gmap, float* __restrict__ bmap)
{
    int idx = blockIdx.x * 256 + threadIdx.x;
    int b = idx >> 12;
    int p = idx & 4095;
    int gy = p >> 6, gx = p & 63;

    float w[NC_];
#pragma unroll
    for (int nc = 0; nc < NC_; ++nc) {
        int yc = centers[b * (NC_ * 2) + nc * 2 + 0];
        int xc = centers[b * (NC_ * 2) + nc * 2 + 1];
        int dy = gy - yc, dx = gx - xc;
        w[nc] = expf(-(float)(dy * dy + dx * dx) / 81.92f);
    }
    float gsum = 0.f, bmx = -1e30f;
#pragma unroll
    for (int c = 0; c < NC_; ++c) {
        float ag = 0.f, ab = 0.f;
#pragma unroll
        for (int ic = 0; ic < NC_; ++ic) {
            ag += wg[c * NC_ + ic] * w[ic];
            ab += wb[c * NC_ + ic] * w[ic];
        }
        gsum += tanhf(siluf(sg[c] * ag + bg[c]));
        bmx = fmaxf(bmx, tanhf(siluf(sb[c] * ab + bb[c])));
    }
    gmap[idx] = gsum * (1.f / (float)NC_);
    bmap[idx] = bmx;
}

// ---------------- MFMA GEMM helpers ----------------
// LDS row stride = 40 shorts (80 B): 16B-aligned rows, ~2-way bank aliasing (free).
static __device__ __forceinline__ void stage_W32(const u16* __restrict__ Wg, int Kst,
                                                 int k0, int t, short* sW)
{
    int ocb = t >> 2, sg = t & 3;
#pragma unroll
    for (int i = 0; i < 4; ++i) {
        int oc = ocb + i * 64;
        uint4 v = *(const uint4*)(Wg + (size_t)oc * Kst + k0 + sg * 8);
        *(uint4*)&sW[oc * 40 + sg * 8] = v;
    }
}
static __device__ __forceinline__ void stage_A32(const u16* __restrict__ Xb, int p0,
                                                 int k0, int t, short* sA)
{
    int pr = t >> 1, hf = t & 1;
    const u16* sp = Xb + (size_t)(p0 + pr) * C_ + k0 + hf * 16;
    uint4 v0 = *(const uint4*)sp;
    uint4 v1 = *(const uint4*)(sp + 8);
    *(uint4*)&sA[pr * 40 + hf * 16] = v0;
    *(uint4*)&sA[pr * 40 + hf * 16 + 8] = v1;
}
static __device__ __forceinline__ void frag_mfma(const short* sA, const short* sW,
                                                 int l15, int q, int w, f32x4 acc[8][4])
{
    bf16x8 a[8];
#pragma unroll
    for (int m = 0; m < 8; ++m)
        a[m] = *(const bf16x8*)&sA[(m * 16 + l15) * 40 + q * 8];
    bf16x8 bb[4];
#pragma unroll
    for (int n = 0; n < 4; ++n)
        bb[n] = *(const bf16x8*)&sW[(w * 64 + n * 16 + l15) * 40 + q * 8];
#pragma unroll
    for (int m = 0; m < 8; ++m)
#pragma unroll
        for (int n = 0; n < 4; ++n)
            acc[m][n] = __builtin_amdgcn_mfma_f32_16x16x32_bf16(a[m], bb[n], acc[m][n], 0, 0, 0);
}

// ---------------- visu conv + FiLM + l2norm -> v_film (bf16 CL) ----------------
__global__ __launch_bounds__(256, 1) void k_visu(
    const u16* __restrict__ X, const u16* __restrict__ W,
    const float* __restrict__ s_visu, const float* __restrict__ b_visu,
    const float* __restrict__ gmap, const float* __restrict__ bmap,
    u16* __restrict__ Y)
{
    int b = blockIdx.y, p0 = blockIdx.x * 128, t = threadIdx.x;
    int l15 = t & 15, q = (t >> 4) & 3, w = t >> 6;
    __shared__ short sA[128 * 40];
    __shared__ short sW[256 * 40];
    __shared__ float red[4][128];
    __shared__ float invs[128];
    const u16* Xb = X + (size_t)b * CP_;

    f32x4 acc[8][4];
#pragma unroll
    for (int m = 0; m < 8; ++m)
#pragma unroll
        for (int n = 0; n < 4; ++n) acc[m][n] = (f32x4)0.f;

    for (int s = 0; s < 8; ++s) {
        stage_A32(Xb, p0, s * 32, t, sA);
        stage_W32(W, 256, s * 32, t, sW);
        __syncthreads();
        frag_mfma(sA, sW, l15, q, w, acc);
        __syncthreads();
    }

    float sc[4], sh[4];
#pragma unroll
    for (int n = 0; n < 4; ++n) {
        int oc = w * 64 + n * 16 + l15;
        sc[n] = s_visu[oc]; sh[n] = b_visu[oc];
    }
#pragma unroll
    for (int m = 0; m < 8; ++m) {
        f32x4 gv = *(const f32x4*)&gmap[(size_t)b * P_ + p0 + m * 16 + q * 4];
        f32x4 bm = *(const f32x4*)&bmap[(size_t)b * P_ + p0 + m * 16 + q * 4];
#pragma unroll
        for (int n = 0; n < 4; ++n)
#pragma unroll
            for (int r = 0; r < 4; ++r) {
                float y = sc[n] * acc[m][n][r] + sh[n];
                float mv = tanhf(siluf(y));
                acc[m][n][r] = gv[r] * mv + bm[r];
            }
    }
    // channel l2norm (over oc)
#pragma unroll
    for (int m = 0; m < 8; ++m)
#pragma unroll
        for (int r = 0; r < 4; ++r) {
            float ps = 0.f;
#pragma unroll
            for (int n = 0; n < 4; ++n) ps += acc[m][n][r] * acc[m][n][r];
            ps += __shfl_xor(ps, 1);
            ps += __shfl_xor(ps, 2);
            ps += __shfl_xor(ps, 4);
            ps += __shfl_xor(ps, 8);
            if (l15 == 0) red[w][m * 16 + q * 4 + r] = ps;
        }
    __syncthreads();
    if (t < 128) {
        float s = red[0][t] + red[1][t] + red[2][t] + red[3][t];
        invs[t] = 1.f / fmaxf(sqrtf(s), 1e-12f);
    }
    __syncthreads();

    u16* Yb = Y + (size_t)b * CP_ + (size_t)p0 * C_;
    short* LO = sA;   // reuse (5120 shorts >= 4096)
#pragma unroll
    for (int m = 0; m < 8; ++m) {
        __syncthreads();
#pragma unroll
        for (int n = 0; n < 4; ++n)
#pragma unroll
            for (int r = 0; r < 4; ++r) {
                float v = acc[m][n][r] * invs[m * 16 + q * 4 + r];
                LO[(q * 4 + r) * 256 + w * 64 + n * 16 + l15] = (short)f2b(v);
            }
        __syncthreads();
        int row = t >> 4, sg = t & 15;
        uint4 o0 = *(const uint4*)&LO[row * 256 + sg * 16];
        uint4 o1 = *(const uint4*)&LO[row * 256 + sg * 16 + 8];
        u16* dp = Yb + (size_t)(m * 16 + row) * C_ + sg * 16;
        *(uint4*)dp = o0;
        *(uint4*)(dp + 8) = o1;
    }
}

// ---------------- 1x1 conv (f1) + silu -> bf16 CL ----------------
__global__ __launch_bounds__(256, 1) void k_f1(
    const u16* __restrict__ X, const u16* __restrict__ W,
    const float* __restrict__ scale, const float* __restrict__ shift,
    u16* __restrict__ Y)
{
    int b = blockIdx.y, p0 = blockIdx.x * 128, t = threadIdx.x;
    int l15 = t & 15, q = (t >> 4) & 3, w = t >> 6;
    __shared__ short sA[128 * 40];
    __shared__ short sW[256 * 40];
    const u16* Xb = X + (size_t)b * CP_;

    f32x4 acc[8][4];
#pragma unroll
    for (int m = 0; m < 8; ++m)
#pragma unroll
        for (int n = 0; n < 4; ++n) acc[m][n] = (f32x4)0.f;

    for (int s = 0; s < 8; ++s) {
        stage_A32(Xb, p0, s * 32, t, sA);
        stage_W32(W, 256, s * 32, t, sW);
        __syncthreads();
        frag_mfma(sA, sW, l15, q, w, acc);
        __syncthreads();
    }

    float sc[4], sh[4];
#pragma unroll
    for (int n = 0; n < 4; ++n) {
        int oc = w * 64 + n * 16 + l15;
        sc[n] = scale[oc]; sh[n] = shift[oc];
    }
    u16* Yb = Y + (size_t)b * CP_ + (size_t)p0 * C_;
    short* LO = sA;
#pragma unroll
    for (int m = 0; m < 8; ++m) {
        __syncthreads();
#pragma unroll
        for (int n = 0; n < 4; ++n)
#pragma unroll
            for (int r = 0; r < 4; ++r) {
                float v = siluf(sc[n] * acc[m][n][r] + sh[n]);
                LO[(q * 4 + r) * 256 + w * 64 + n * 16 + l15] = (short)f2b(v);
            }
        __syncthreads();
        int row = t >> 4, sg = t & 15;
        uint4 o0 = *(const uint4*)&LO[row * 256 + sg * 16];
        uint4 o1 = *(const uint4*)&LO[row * 256 + sg * 16 + 8];
        u16* dp = Yb + (size_t)(m * 16 + row) * C_ + sg * 16;
        *(uint4*)dp = o0;
        *(uint4*)(dp + 8) = o1;
    }
}

// ---------------- 3x3 conv (f2) + silu -> bf16 CL ----------------
__global__ __launch_bounds__(256, 1) void k_f2(
    const u16* __restrict__ X, const u16* __restrict__ W,
    const float* __restrict__ scale, const float* __restrict__ shift,
    u16* __restrict__ Y)
{
    int b = blockIdx.y, p0 = blockIdx.x * 128, t = threadIdx.x;
    int l15 = t & 15, q = (t >> 4) & 3, w = t >> 6;
    __shared__ short sA[128 * 40];
    __shared__ short sW[256 * 40];
    const u16* Xb = X + (size_t)b * CP_;

    f32x4 acc[8][4];
#pragma unroll
    for (int m = 0; m < 8; ++m)
#pragma unroll
        for (int n = 0; n < 4; ++n) acc[m][n] = (f32x4)0.f;

    for (int s = 0; s < 72; ++s) {
        int k0 = s * 32;
        int tap = k0 >> 8;
        int icb = k0 & 255;
        int dy = tap / 3 - 1, dx = tap - (tap / 3) * 3 - 1;
        {
            int pr = t >> 1, hf = t & 1;
            int op = p0 + pr;
            int hs = (op >> 6) + dy, xs = (op & 63) + dx;
            uint4 v0 = make_uint4(0, 0, 0, 0), v1 = make_uint4(0, 0, 0, 0);
            if ((unsigned)hs < (unsigned)HH && (unsigned)xs < (unsigned)HH) {
                const u16* sp = Xb + (size_t)(hs * HH + xs) * C_ + icb + hf * 16;
                v0 = *(const uint4*)sp;
                v1 = *(const uint4*)(sp + 8);
            }
            *(uint4*)&sA[pr * 40 + hf * 16] = v0;
            *(uint4*)&sA[pr * 40 + hf * 16 + 8] = v1;
        }
        stage_W32(W, 2304, k0, t, sW);
        __syncthreads();
        frag_mfma(sA, sW, l15, q, w, acc);
        __syncthreads();
    }

    float sc[4], sh[4];
#pragma unroll
    for (int n = 0; n < 4; ++n) {
        int oc = w * 64 + n * 16 + l15;
        sc[n] = scale[oc]; sh[n] = shift[oc];
    }
    u16* Yb = Y + (size_t)b * CP_ + (size_t)p0 * C_;
    short* LO = sA;
#pragma unroll
    for (int m = 0; m < 8; ++m) {
        __syncthreads();
#pragma unroll
        for (int n = 0; n < 4; ++n)
#pragma unroll
            for (int r = 0; r < 4; ++r) {
                float v = siluf(sc[n] * acc[m][n][r] + sh[n]);
                LO[(q * 4 + r) * 256 + w * 64 + n * 16 + l15] = (short)f2b(v);
            }
        __syncthreads();
        int row = t >> 4, sg = t & 15;
        uint4 o0 = *(const uint4*)&LO[row * 256 + sg * 16];
        uint4 o1 = *(const uint4*)&LO[row * 256 + sg * 16 + 8];
        u16* dp = Yb + (size_t)(m * 16 + row) * C_ + sg * 16;
        *(uint4*)dp = o0;
        *(uint4*)(dp + 8) = o1;
    }
}

// ---------------- f3 conv + bias + v_add + l2norm -> out (fp32 CF) ----------------
__global__ __launch_bounds__(256, 1) void k_final(
    const u16* __restrict__ X, const u16* __restrict__ W,
    const float* __restrict__ bias_f3, const float* __restrict__ img,
    const float* __restrict__ add_w, float* __restrict__ out)
{
    int b = blockIdx.y, p0 = blockIdx.x * 128, t = threadIdx.x;
    int l15 = t & 15, q = (t >> 4) & 3, w = t >> 6;
    __shared__ short sA[128 * 40];
    __shared__ short sW[256 * 40];
    __shared__ float red[4][128];
    __shared__ float invs[128];
    const u16* Xb = X + (size_t)b * CP_;

    f32x4 acc[8][4];
#pragma unroll
    for (int m = 0; m < 8; ++m)
#pragma unroll
        for (int n = 0; n < 4; ++n) acc[m][n] = (f32x4)0.f;

    for (int s = 0; s < 8; ++s) {
        stage_A32(Xb, p0, s * 32, t, sA);
        stage_W32(W, 256, s * 32, t, sW);
        __syncthreads();
        frag_mfma(sA, sW, l15, q, w, acc);
        __syncthreads();
    }

    float aw = tanhf(add_w[0]);
    float c1 = 1.f + aw, c2 = 1.f - aw;
    float bf[4];
#pragma unroll
    for (int n = 0; n < 4; ++n) bf[n] = bias_f3[w * 64 + n * 16 + l15];

#pragma unroll
    for (int m = 0; m < 8; ++m)
#pragma unroll
        for (int n = 0; n < 4; ++n) {
            int oc = w * 64 + n * 16 + l15;
            f32x4 iv = *(const f32x4*)&img[((size_t)b * C_ + oc) * P_ + p0 + m * 16 + q * 4];
#pragma unroll
            for (int r = 0; r < 4; ++r)
                acc[m][n][r] = c1 * iv[r] + c2 * (acc[m][n][r] + bf[n]);
        }
#pragma unroll
    for (int m = 0; m < 8; ++m)
#pragma unroll
        for (int r = 0; r < 4; ++r) {
            float ps = 0.f;
#pragma unroll
            for (int n = 0; n < 4; ++n) ps += acc[m][n][r] * acc[m][n][r];
            ps += __shfl_xor(ps, 1);
            ps += __shfl_xor(ps, 2);
            ps += __shfl_xor(ps, 4);
            ps += __shfl_xor(ps, 8);
            if (l15 == 0) red[w][m * 16 + q * 4 + r] = ps;
        }
    __syncthreads();
    if (t < 128) {
        float s = red[0][t] + red[1][t] + red[2][t] + red[3][t];
        invs[t] = 1.f / fmaxf(sqrtf(s), 1e-12f);
    }
    __syncthreads();
#pragma unroll
    for (int m = 0; m < 8; ++m) {
        f32x4 iv = *(const f32x4*)&invs[m * 16 + q * 4];
#pragma unroll
        for (int n = 0; n < 4; ++n) {
            int oc = w * 64 + n * 16 + l15;
            f32x4 o;
#pragma unroll
            for (int r = 0; r < 4; ++r) o[r] = acc[m][n][r] * iv[r];
            *(f32x4*)&out[((size_t)b * C_ + oc) * P_ + p0 + m * 16 + q * 4] = o;
        }
    }
}

extern "C" void kernel_launch(void* const* d_in, const int* in_sizes, int n_in,
                              void* d_out, int out_size, void* d_ws, size_t ws_size,
                              hipStream_t stream)
{
    const float* img     = (const float*)d_in[0];
    const float* flang   = (const float*)d_in[1];
    const int*   wmask   = (const int*)d_in[2];
    const float* w_visu  = (const float*)d_in[3];
    const float* s_visu  = (const float*)d_in[4];
    const float* b_visu  = (const float*)d_in[5];
    const float* w_g     = (const float*)d_in[6];
    const float* s_g     = (const float*)d_in[7];
    const float* b_g     = (const float*)d_in[8];
    const float* w_b     = (const float*)d_in[9];
    const float* s_b     = (const float*)d_in[10];
    const float* b_b     = (const float*)d_in[11];
    const float* W1      = (const float*)d_in[12];
    const float* b1      = (const float*)d_in[13];
    const float* W2      = (const float*)d_in[14];
    const float* b2      = (const float*)d_in[15];
    const float* w_f1    = (const float*)d_in[16];
    const float* s_f1    = (const float*)d_in[17];
    const float* b_f1    = (const float*)d_in[18];
    const float* w_f2    = (const float*)d_in[19];
    const float* s_f2    = (const float*)d_in[20];
    const float* b_f2    = (const float*)d_in[21];
    const float* w_f3    = (const float*)d_in[22];
    const float* bias_f3 = (const float*)d_in[23];
    const float* add_w   = (const float*)d_in[24];

    float* out = (float*)d_out;

    // workspace layout (u16 elements)
    u16* bigA = (u16*)d_ws;                 // 33554432: v_film, then v2
    u16* bigB = bigA + (size_t)B_ * CP_;    // 33554432: imgT, then v
    u16* WV   = bigB + (size_t)B_ * CP_;    // 65536
    u16* WF1  = WV + 65536;                 // 65536
    u16* WF3  = WF1 + 65536;                // 65536
    u16* WF2  = WF3 + 65536;                // 589824
    float* gmap = (float*)(WF2 + 589824);   // 131072 f32
    float* bmap = gmap + (size_t)B_ * P_;   // 131072 f32
    int* centers = (int*)(bmap + (size_t)B_ * P_);

    k_prep<<<256, 256, 0, stream>>>(w_visu, w_f1, w_f3, w_f2, WV, WF1, WF3, WF2);
    k_lang<<<B_, 256, 0, stream>>>(flang, wmask, W1, b1, W2, b2, centers);
    k_gb<<<(B_ * P_) / 256, 256, 0, stream>>>(centers, w_g, s_g, b_g, w_b, s_b, b_b, gmap, bmap);
    k_imgT<<<dim3(P_ / 32, C_ / 32, B_), 256, 0, stream>>>(img, bigB);
    k_visu<<<dim3(P_ / 128, B_), 256, 0, stream>>>(bigB, WV, s_visu, b_visu, gmap, bmap, bigA);
    k_f1<<<dim3(P_ / 128, B_), 256, 0, stream>>>(bigA, WF1, s_f1, b_f1, bigB);
    k_f2<<<dim3(P_ / 128, B_), 256, 0, stream>>>(bigB, WF2, s_f2, b_f2, bigA);
    k_final<<<dim3(P_ / 128, B_), 256, 0, stream>>>(bigA, WF3, bias_f3, img, add_w, out);
}

// Round 5
// 577.676 us; speedup vs baseline: 5.5571x; 1.3983x over previous
//
#include <hip/hip_runtime.h>
#include <hip/hip_bf16.h>

#define B_   32
#define C_   256
#define HH   64
#define P_   4096   // 64*64
#define L_   40
#define D_   768
#define NC_  8
#define EMB_ 392
#define CP_  (C_*P_)   // 1048576

typedef __attribute__((ext_vector_type(8))) short bf16x8;
typedef __attribute__((ext_vector_type(4))) float f32x4;
typedef unsigned short u16;

static __device__ __forceinline__ float siluf(float y) {
    return y / (1.f + expf(-y));
}
static __device__ __forceinline__ u16 f2b(float f) {
    __hip_bfloat16 h = __float2bfloat16(f);
    return *reinterpret_cast<u16*>(&h);
}

typedef __attribute__((address_space(1))) const unsigned int g_u32;
typedef __attribute__((address_space(3))) unsigned int l_u32;
static __device__ __forceinline__ void gl_lds(const u16* g, short* l) {
    __builtin_amdgcn_global_load_lds((g_u32*)g, (l_u32*)l, 16, 0, 0);
}

// ---------------- weight pack to bf16 + zero block ----------------
// WV/WF1/WF3: [oc][ic] ; WF2: [oc][tap*256+ic]  (K-contiguous rows)
__global__ __launch_bounds__(256) void k_prep(
    const float* __restrict__ wv, const float* __restrict__ wf1,
    const float* __restrict__ wf3, const float* __restrict__ wf2,
    u16* __restrict__ WV, u16* __restrict__ WF1,
    u16* __restrict__ WF3, u16* __restrict__ WF2, u16* __restrict__ zblk)
{
    int i = blockIdx.x * 256 + threadIdx.x;   // i = oc*256 + ic
    int oc = i >> 8, ic = i & 255;
    WV[i]  = f2b(wv[i]);
    WF1[i] = f2b(wf1[i]);
    WF3[i] = f2b(wf3[i]);
#pragma unroll
    for (int tap = 0; tap < 9; ++tap)
        WF2[oc * 2304 + tap * 256 + ic] = f2b(wf2[oc * 2304 + ic * 9 + tap]);
    if (blockIdx.x == 0 && threadIdx.x < 16) zblk[threadIdx.x] = 0;
}

// ---------------- img -> channels-last bf16 ----------------
__global__ __launch_bounds__(256) void k_imgT(
    const float* __restrict__ img, u16* __restrict__ imgT)
{
    int b = blockIdx.z, pix0 = blockIdx.x * 32, ic0 = blockIdx.y * 32;
    int t = threadIdx.x;
    __shared__ float T[32][33];
    int ic = t >> 3, ps = (t & 7) * 4;
    f32x4 v = *(const f32x4*)&img[((size_t)b * C_ + ic0 + ic) * P_ + pix0 + ps];
    T[ic][ps] = v[0]; T[ic][ps + 1] = v[1]; T[ic][ps + 2] = v[2]; T[ic][ps + 3] = v[3];
    __syncthreads();
    int px = t >> 3, sg = (t & 7) * 4;
    u16 o0 = f2b(T[sg + 0][px]), o1 = f2b(T[sg + 1][px]);
    u16 o2 = f2b(T[sg + 2][px]), o3 = f2b(T[sg + 3][px]);
    uint2 val;
    val.x = (unsigned)o0 | ((unsigned)o1 << 16);
    val.y = (unsigned)o2 | ((unsigned)o3 << 16);
    *(uint2*)(imgT + ((size_t)b * P_ + pix0 + px) * C_ + ic0 + sg) = val;
}

// ---------------- language path (fp32) ----------------
__global__ __launch_bounds__(256) void k_lang(
    const float* __restrict__ flang, const int* __restrict__ wmask,
    const float* __restrict__ W1, const float* __restrict__ b1,
    const float* __restrict__ W2, const float* __restrict__ b2,
    int* __restrict__ centers)
{
    int b = blockIdx.x, tid = threadIdx.x;
    __shared__ float inner[L_];
    __shared__ float cnt_s;
    __shared__ float favg[D_];
    __shared__ float hbuf[EMB_];
    __shared__ float mfs[16];

    if (tid == 0) {
        int total = 0;
        for (int l = 0; l < L_; ++l) total += wmask[b * L_ + l];
        int c = 0, cntv = 0;
        for (int l = 0; l < L_; ++l) {
            int m = wmask[b * L_ + l];
            c += m;
            float f = (m == 1 && c > 1 && c < total) ? 1.f : 0.f;
            inner[l] = f;
            cntv += (f != 0.f);
        }
        cnt_s = (float)cntv;
    }
    __syncthreads();
    float cinv = 1.f / cnt_s;
    for (int d = tid; d < D_; d += 256) {
        float s = 0.f;
        for (int l = 0; l < L_; ++l)
            s += flang[((size_t)b * L_ + l) * D_ + d] * inner[l];
        favg[d] = s * cinv;
    }
    __syncthreads();
    for (int e = tid; e < EMB_; e += 256) {
        float s = b1[e];
        const float* w = W1 + (size_t)e * D_;
        for (int d = 0; d < D_; ++d) s += w[d] * favg[d];
        hbuf[e] = s;
    }
    __syncthreads();
    if (tid < 16) {
        float s = b2[tid];
        const float* w = W2 + tid * EMB_;
        for (int d = 0; d < EMB_; ++d) s += w[d] * hbuf[d];
        mfs[tid] = 1.f / (1.f + expf(-s));
    }
    __syncthreads();
    if (tid < NC_) {
        centers[b * (NC_ * 2) + tid * 2 + 0] = (int)(mfs[tid * 2 + 0] * (float)HH);
        centers[b * (NC_ * 2) + tid * 2 + 1] = (int)(mfs[tid * 2 + 1] * (float)HH);
    }
}

// ---------------- gaussian -> gamma/beta maps (fp32) ----------------
__global__ __launch_bounds__(256) void k_gb(
    const int* __restrict__ centers,
    const float* __restrict__ wg, const float* __restrict__ sg, const float* __restrict__ bg,
    const float* __restrict__ wb, const float* __restrict__ sb, const float* __restrict__ bb,
    float* __restrict__ gmap, float* __restrict__ bmap)
{
    int idx = blockIdx.x * 256 + threadIdx.x;
    int b = idx >> 12;
    int p = idx & 4095;
    int gy = p >> 6, gx = p & 63;

    float w[NC_];
#pragma unroll
    for (int nc = 0; nc < NC_; ++nc) {
        int yc = centers[b * (NC_ * 2) + nc * 2 + 0];
        int xc = centers[b * (NC_ * 2) + nc * 2 + 1];
        int dy = gy - yc, dx = gx - xc;
        w[nc] = expf(-(float)(dy * dy + dx * dx) / 81.92f);
    }
    float gsum = 0.f, bmx = -1e30f;
#pragma unroll
    for (int c = 0; c < NC_; ++c) {
        float ag = 0.f, ab = 0.f;
#pragma unroll
        for (int ic = 0; ic < NC_; ++ic) {
            ag += wg[c * NC_ + ic] * w[ic];
            ab += wb[c * NC_ + ic] * w[ic];
        }
        gsum += tanhf(siluf(sg[c] * ag + bg[c]));
        bmx = fmaxf(bmx, tanhf(siluf(sb[c] * ab + bb[c])));
    }
    gmap[idx] = gsum * (1.f / (float)NC_);
    bmap[idx] = bmx;
}

// ---------------- MFMA helpers ----------------
// LDS layout: linear 64B rows ([row][32ch]), chunk-XOR swizzle pc = c ^ ((row>>1)&3)
// applied identically on the staging source address and the ds_read address.
static __device__ __forceinline__ void frag_mfma(const short* sA, const short* sW,
                                                 int l15, int qa, int w, f32x4 acc[8][4])
{
    bf16x8 a[8];
#pragma unroll
    for (int m = 0; m < 8; ++m)
        a[m] = *(const bf16x8*)&sA[(m * 16 + l15) * 32 + qa * 8];
    bf16x8 bb[4];
#pragma unroll
    for (int n = 0; n < 4; ++n)
        bb[n] = *(const bf16x8*)&sW[(w * 64 + n * 16 + l15) * 32 + qa * 8];
#pragma unroll
    for (int m = 0; m < 8; ++m)
#pragma unroll
        for (int n = 0; n < 4; ++n)
            acc[m][n] = __builtin_amdgcn_mfma_f32_16x16x32_bf16(a[m], bb[n], acc[m][n], 0, 0, 0);
}

// ---------------- visu conv + FiLM + l2norm -> v_film (bf16 CL) ----------------
__global__ __launch_bounds__(256, 2) void k_visu(
    const u16* __restrict__ X, const u16* __restrict__ W,
    const float* __restrict__ s_visu, const float* __restrict__ b_visu,
    const float* __restrict__ gmap, const float* __restrict__ bmap,
    u16* __restrict__ Y)
{
    int b = blockIdx.y, p0 = blockIdx.x * 128, t = threadIdx.x;
    int lane = t & 63, w = t >> 6;
    int l15 = t & 15, q = (t >> 4) & 3;
    int qa = q ^ ((l15 >> 1) & 3);
    int lc = (lane & 3) ^ ((lane >> 3) & 3);
    int lp = lane >> 2;
    __shared__ short sA[128 * 32];
    __shared__ short sW[256 * 32];
    __shared__ float red[4][128];
    __shared__ float invs[128];
    const u16* Xb = X + (size_t)b * CP_;

    f32x4 acc[8][4];
#pragma unroll
    for (int m = 0; m < 8; ++m)
#pragma unroll
        for (int n = 0; n < 4; ++n) acc[m][n] = (f32x4)0.f;

    for (int s = 0; s < 8; ++s) {
        int k0 = s * 32;
#pragma unroll
        for (int i = 0; i < 2; ++i) {
            int pr = (w * 2 + i) * 16 + lp;
            gl_lds(Xb + (size_t)(p0 + pr) * C_ + k0 + lc * 8, &sA[(w * 2 + i) * 512]);
        }
#pragma unroll
        for (int j = 0; j < 4; ++j) {
            int oc = (w * 4 + j) * 16 + lp;
            gl_lds(W + (size_t)oc * 256 + k0 + lc * 8, &sW[(w * 4 + j) * 512]);
        }
        __syncthreads();
        frag_mfma(sA, sW, l15, qa, w, acc);
        __syncthreads();
    }

    float sc[4], sh[4];
#pragma unroll
    for (int n = 0; n < 4; ++n) {
        int oc = w * 64 + n * 16 + l15;
        sc[n] = s_visu[oc]; sh[n] = b_visu[oc];
    }
#pragma unroll
    for (int m = 0; m < 8; ++m) {
        f32x4 gv = *(const f32x4*)&gmap[(size_t)b * P_ + p0 + m * 16 + q * 4];
        f32x4 bm = *(const f32x4*)&bmap[(size_t)b * P_ + p0 + m * 16 + q * 4];
#pragma unroll
        for (int n = 0; n < 4; ++n)
#pragma unroll
            for (int r = 0; r < 4; ++r) {
                float y = sc[n] * acc[m][n][r] + sh[n];
                float mv = tanhf(siluf(y));
                acc[m][n][r] = gv[r] * mv + bm[r];
            }
    }
    // channel l2norm (over oc)
#pragma unroll
    for (int m = 0; m < 8; ++m)
#pragma unroll
        for (int r = 0; r < 4; ++r) {
            float ps = 0.f;
#pragma unroll
            for (int n = 0; n < 4; ++n) ps += acc[m][n][r] * acc[m][n][r];
            ps += __shfl_xor(ps, 1);
            ps += __shfl_xor(ps, 2);
            ps += __shfl_xor(ps, 4);
            ps += __shfl_xor(ps, 8);
            if (l15 == 0) red[w][m * 16 + q * 4 + r] = ps;
        }
    __syncthreads();
    if (t < 128) {
        float s = red[0][t] + red[1][t] + red[2][t] + red[3][t];
        invs[t] = 1.f / fmaxf(sqrtf(s), 1e-12f);
    }
    __syncthreads();

    u16* Yb = Y + (size_t)b * CP_ + (size_t)p0 * C_;
    short* LO = sA;   // reuse (4096 shorts)
#pragma unroll
    for (int m = 0; m < 8; ++m) {
        __syncthreads();
#pragma unroll
        for (int n = 0; n < 4; ++n)
#pragma unroll
            for (int r = 0; r < 4; ++r) {
                float v = acc[m][n][r] * invs[m * 16 + q * 4 + r];
                LO[(q * 4 + r) * 256 + w * 64 + n * 16 + l15] = (short)f2b(v);
            }
        __syncthreads();
        int row = t >> 4, sg = t & 15;
        uint4 o0 = *(const uint4*)&LO[row * 256 + sg * 16];
        uint4 o1 = *(const uint4*)&LO[row * 256 + sg * 16 + 8];
        u16* dp = Yb + (size_t)(m * 16 + row) * C_ + sg * 16;
        *(uint4*)dp = o0;
        *(uint4*)(dp + 8) = o1;
    }
}

// ---------------- 1x1 conv (f1) + silu -> bf16 CL ----------------
__global__ __launch_bounds__(256, 2) void k_f1(
    const u16* __restrict__ X, const u16* __restrict__ W,
    const float* __restrict__ scale, const float* __restrict__ shift,
    u16* __restrict__ Y)
{
    int b = blockIdx.y, p0 = blockIdx.x * 128, t = threadIdx.x;
    int lane = t & 63, w = t >> 6;
    int l15 = t & 15, q = (t >> 4) & 3;
    int qa = q ^ ((l15 >> 1) & 3);
    int lc = (lane & 3) ^ ((lane >> 3) & 3);
    int lp = lane >> 2;
    __shared__ short sA[128 * 32];
    __shared__ short sW[256 * 32];
    const u16* Xb = X + (size_t)b * CP_;

    f32x4 acc[8][4];
#pragma unroll
    for (int m = 0; m < 8; ++m)
#pragma unroll
        for (int n = 0; n < 4; ++n) acc[m][n] = (f32x4)0.f;

    for (int s = 0; s < 8; ++s) {
        int k0 = s * 32;
#pragma unroll
        for (int i = 0; i < 2; ++i) {
            int pr = (w * 2 + i) * 16 + lp;
            gl_lds(Xb + (size_t)(p0 + pr) * C_ + k0 + lc * 8, &sA[(w * 2 + i) * 512]);
        }
#pragma unroll
        for (int j = 0; j < 4; ++j) {
            int oc = (w * 4 + j) * 16 + lp;
            gl_lds(W + (size_t)oc * 256 + k0 + lc * 8, &sW[(w * 4 + j) * 512]);
        }
        __syncthreads();
        frag_mfma(sA, sW, l15, qa, w, acc);
        __syncthreads();
    }

    float sc[4], sh[4];
#pragma unroll
    for (int n = 0; n < 4; ++n) {
        int oc = w * 64 + n * 16 + l15;
        sc[n] = scale[oc]; sh[n] = shift[oc];
    }
    u16* Yb = Y + (size_t)b * CP_ + (size_t)p0 * C_;
    short* LO = sA;
#pragma unroll
    for (int m = 0; m < 8; ++m) {
        __syncthreads();
#pragma unroll
        for (int n = 0; n < 4; ++n)
#pragma unroll
            for (int r = 0; r < 4; ++r) {
                float v = siluf(sc[n] * acc[m][n][r] + sh[n]);
                LO[(q * 4 + r) * 256 + w * 64 + n * 16 + l15] = (short)f2b(v);
            }
        __syncthreads();
        int row = t >> 4, sg = t & 15;
        uint4 o0 = *(const uint4*)&LO[row * 256 + sg * 16];
        uint4 o1 = *(const uint4*)&LO[row * 256 + sg * 16 + 8];
        u16* dp = Yb + (size_t)(m * 16 + row) * C_ + sg * 16;
        *(uint4*)dp = o0;
        *(uint4*)(dp + 8) = o1;
    }
}

// ---------------- 3x3 conv (f2) + silu -> bf16 CL ----------------
__global__ __launch_bounds__(256, 2) void k_f2(
    const u16* __restrict__ X, const u16* __restrict__ W,
    const float* __restrict__ scale, const float* __restrict__ shift,
    const u16* __restrict__ zblk, u16* __restrict__ Y)
{
    int b = blockIdx.y, p0 = blockIdx.x * 128, t = threadIdx.x;
    int lane = t & 63, w = t >> 6;
    int l15 = t & 15, q = (t >> 4) & 3;
    int qa = q ^ ((l15 >> 1) & 3);
    int lc = (lane & 3) ^ ((lane >> 3) & 3);
    int lp = lane >> 2;
    __shared__ short sA[128 * 32];
    __shared__ short sW[256 * 32];
    const u16* Xb = X + (size_t)b * CP_;

    f32x4 acc[8][4];
#pragma unroll
    for (int m = 0; m < 8; ++m)
#pragma unroll
        for (int n = 0; n < 4; ++n) acc[m][n] = (f32x4)0.f;

    for (int s = 0; s < 72; ++s) {
        int k0 = s * 32;
        int tap = s >> 3;
        int icb = (s & 7) * 32;
        int dy = tap / 3 - 1, dx = tap - (tap / 3) * 3 - 1;
#pragma unroll
        for (int i = 0; i < 2; ++i) {
            int pr = (w * 2 + i) * 16 + lp;
            int p = p0 + pr;
            int y = (p >> 6) + dy, x = (p & 63) + dx;
            const u16* gp = ((unsigned)y < (unsigned)HH && (unsigned)x < (unsigned)HH)
                ? Xb + (size_t)(y * HH + x) * C_ + icb + lc * 8
                : zblk;
            gl_lds(gp, &sA[(w * 2 + i) * 512]);
        }
#pragma unroll
        for (int j = 0; j < 4; ++j) {
            int oc = (w * 4 + j) * 16 + lp;
            gl_lds(W + (size_t)oc * 2304 + k0 + lc * 8, &sW[(w * 4 + j) * 512]);
        }
        __syncthreads();
        frag_mfma(sA, sW, l15, qa, w, acc);
        __syncthreads();
    }

    float sc[4], sh[4];
#pragma unroll
    for (int n = 0; n < 4; ++n) {
        int oc = w * 64 + n * 16 + l15;
        sc[n] = scale[oc]; sh[n] = shift[oc];
    }
    u16* Yb = Y + (size_t)b * CP_ + (size_t)p0 * C_;
    short* LO = sA;
#pragma unroll
    for (int m = 0; m < 8; ++m) {
        __syncthreads();
#pragma unroll
        for (int n = 0; n < 4; ++n)
#pragma unroll
            for (int r = 0; r < 4; ++r) {
                float v = siluf(sc[n] * acc[m][n][r] + sh[n]);
                LO[(q * 4 + r) * 256 + w * 64 + n * 16 + l15] = (short)f2b(v);
            }
        __syncthreads();
        int row = t >> 4, sg = t & 15;
        uint4 o0 = *(const uint4*)&LO[row * 256 + sg * 16];
        uint4 o1 = *(const uint4*)&LO[row * 256 + sg * 16 + 8];
        u16* dp = Yb + (size_t)(m * 16 + row) * C_ + sg * 16;
        *(uint4*)dp = o0;
        *(uint4*)(dp + 8) = o1;
    }
}

// ---------------- f3 conv + bias + v_add + l2norm -> out (fp32 CF) ----------------
__global__ __launch_bounds__(256, 2) void k_final(
    const u16* __restrict__ X, const u16* __restrict__ W,
    const float* __restrict__ bias_f3, const float* __restrict__ img,
    const float* __restrict__ add_w, float* __restrict__ out)
{
    int b = blockIdx.y, p0 = blockIdx.x * 128, t = threadIdx.x;
    int lane = t & 63, w = t >> 6;
    int l15 = t & 15, q = (t >> 4) & 3;
    int qa = q ^ ((l15 >> 1) & 3);
    int lc = (lane & 3) ^ ((lane >> 3) & 3);
    int lp = lane >> 2;
    __shared__ short sA[128 * 32];
    __shared__ short sW[256 * 32];
    __shared__ float red[4][128];
    __shared__ float invs[128];
    const u16* Xb = X + (size_t)b * CP_;

    f32x4 acc[8][4];
#pragma unroll
    for (int m = 0; m < 8; ++m)
#pragma unroll
        for (int n = 0; n < 4; ++n) acc[m][n] = (f32x4)0.f;

    for (int s = 0; s < 8; ++s) {
        int k0 = s * 32;
#pragma unroll
        for (int i = 0; i < 2; ++i) {
            int pr = (w * 2 + i) * 16 + lp;
            gl_lds(Xb + (size_t)(p0 + pr) * C_ + k0 + lc * 8, &sA[(w * 2 + i) * 512]);
        }
#pragma unroll
        for (int j = 0; j < 4; ++j) {
            int oc = (w * 4 + j) * 16 + lp;
            gl_lds(W + (size_t)oc * 256 + k0 + lc * 8, &sW[(w * 4 + j) * 512]);
        }
        __syncthreads();
        frag_mfma(sA, sW, l15, qa, w, acc);
        __syncthreads();
    }

    float aw = tanhf(add_w[0]);
    float c1 = 1.f + aw, c2 = 1.f - aw;
    float bf[4];
#pragma unroll
    for (int n = 0; n < 4; ++n) bf[n] = bias_f3[w * 64 + n * 16 + l15];

#pragma unroll
    for (int m = 0; m < 8; ++m)
#pragma unroll
        for (int n = 0; n < 4; ++n) {
            int oc = w * 64 + n * 16 + l15;
            f32x4 iv = *(const f32x4*)&img[((size_t)b * C_ + oc) * P_ + p0 + m * 16 + q * 4];
#pragma unroll
            for (int r = 0; r < 4; ++r)
                acc[m][n][r] = c1 * iv[r] + c2 * (acc[m][n][r] + bf[n]);
        }
#pragma unroll
    for (int m = 0; m < 8; ++m)
#pragma unroll
        for (int r = 0; r < 4; ++r) {
            float ps = 0.f;
#pragma unroll
            for (int n = 0; n < 4; ++n) ps += acc[m][n][r] * acc[m][n][r];
            ps += __shfl_xor(ps, 1);
            ps += __shfl_xor(ps, 2);
            ps += __shfl_xor(ps, 4);
            ps += __shfl_xor(ps, 8);
            if (l15 == 0) red[w][m * 16 + q * 4 + r] = ps;
        }
    __syncthreads();
    if (t < 128) {
        float s = red[0][t] + red[1][t] + red[2][t] + red[3][t];
        invs[t] = 1.f / fmaxf(sqrtf(s), 1e-12f);
    }
    __syncthreads();
#pragma unroll
    for (int m = 0; m < 8; ++m) {
        f32x4 iv = *(const f32x4*)&invs[m * 16 + q * 4];
#pragma unroll
        for (int n = 0; n < 4; ++n) {
            int oc = w * 64 + n * 16 + l15;
            f32x4 o;
#pragma unroll
            for (int r = 0; r < 4; ++r) o[r] = acc[m][n][r] * iv[r];
            *(f32x4*)&out[((size_t)b * C_ + oc) * P_ + p0 + m * 16 + q * 4] = o;
        }
    }
}

extern "C" void kernel_launch(void* const* d_in, const int* in_sizes, int n_in,
                              void* d_out, int out_size, void* d_ws, size_t ws_size,
                              hipStream_t stream)
{
    const float* img     = (const float*)d_in[0];
    const float* flang   = (const float*)d_in[1];
    const int*   wmask   = (const int*)d_in[2];
    const float* w_visu  = (const float*)d_in[3];
    const float* s_visu  = (const float*)d_in[4];
    const float* b_visu  = (const float*)d_in[5];
    const float* w_g     = (const float*)d_in[6];
    const float* s_g     = (const float*)d_in[7];
    const float* b_g     = (const float*)d_in[8];
    const float* w_b     = (const float*)d_in[9];
    const float* s_b     = (const float*)d_in[10];
    const float* b_b     = (const float*)d_in[11];
    const float* W1      = (const float*)d_in[12];
    const float* b1      = (const float*)d_in[13];
    const float* W2      = (const float*)d_in[14];
    const float* b2      = (const float*)d_in[15];
    const float* w_f1    = (const float*)d_in[16];
    const float* s_f1    = (const float*)d_in[17];
    const float* b_f1    = (const float*)d_in[18];
    const float* w_f2    = (const float*)d_in[19];
    const float* s_f2    = (const float*)d_in[20];
    const float* b_f2    = (const float*)d_in[21];
    const float* w_f3    = (const float*)d_in[22];
    const float* bias_f3 = (const float*)d_in[23];
    const float* add_w   = (const float*)d_in[24];

    float* out = (float*)d_out;

    // workspace layout (u16 elements)
    u16* bigA = (u16*)d_ws;                 // 33554432: v_film, then v2
    u16* bigB = bigA + (size_t)B_ * CP_;    // 33554432: imgT, then v
    u16* WV   = bigB + (size_t)B_ * CP_;    // 65536
    u16* WF1  = WV + 65536;                 // 65536
    u16* WF3  = WF1 + 65536;                // 65536
    u16* WF2  = WF3 + 65536;                // 589824
    float* gmap = (float*)(WF2 + 589824);   // 131072 f32
    float* bmap = gmap + (size_t)B_ * P_;   // 131072 f32
    int* centers = (int*)(bmap + (size_t)B_ * P_);  // 512 ints
    u16* zblk = (u16*)(centers + 512);      // 16 u16 (32B, 16B-aligned)

    k_prep<<<256, 256, 0, stream>>>(w_visu, w_f1, w_f3, w_f2, WV, WF1, WF3, WF2, zblk);
    k_lang<<<B_, 256, 0, stream>>>(flang, wmask, W1, b1, W2, b2, centers);
    k_gb<<<(B_ * P_) / 256, 256, 0, stream>>>(centers, w_g, s_g, b_g, w_b, s_b, b_b, gmap, bmap);
    k_imgT<<<dim3(P_ / 32, C_ / 32, B_), 256, 0, stream>>>(img, bigB);
    k_visu<<<dim3(P_ / 128, B_), 256, 0, stream>>>(bigB, WV, s_visu, b_visu, gmap, bmap, bigA);
    k_f1<<<dim3(P_ / 128, B_), 256, 0, stream>>>(bigA, WF1, s_f1, b_f1, bigB);
    k_f2<<<dim3(P_ / 128, B_), 256, 0, stream>>>(bigB, WF2, s_f2, b_f2, zblk, bigA);
    k_final<<<dim3(P_ / 128, B_), 256, 0, stream>>>(bigA, WF3, bias_f3, img, add_w, out);
}